// Round 1
// baseline (771.795 us; speedup 1.0000x reference)
//
#include <hip/hip_runtime.h>

#define HID 64
#define BN_EPS 1e-5f

// ---------------------------------------------------------------------------
// CSR build: histogram -> single-block scan -> scatter
// ---------------------------------------------------------------------------
__global__ void hist_kernel(const int* __restrict__ dst, int* __restrict__ deg, int E) {
    int e = blockIdx.x * blockDim.x + threadIdx.x;
    if (e < E) atomicAdd(&deg[dst[e]], 1);
}

__global__ __launch_bounds__(1024) void scan_kernel(const int* __restrict__ deg,
                                                    int* __restrict__ rowptr,
                                                    int* __restrict__ cursor, int n) {
    __shared__ int sums[1024];
    int tid = threadIdx.x;
    int ch = (n + 1023) / 1024;
    int begin = tid * ch;
    int end = begin + ch; if (end > n) end = n;
    int s = 0;
    for (int i = begin; i < end; ++i) s += deg[i];
    sums[tid] = s;
    __syncthreads();
    for (int off = 1; off < 1024; off <<= 1) {
        int v = (tid >= off) ? sums[tid - off] : 0;
        __syncthreads();
        sums[tid] += v;
        __syncthreads();
    }
    int run = (tid == 0) ? 0 : sums[tid - 1];
    for (int i = begin; i < end; ++i) {
        rowptr[i] = run; cursor[i] = run;
        run += deg[i];
    }
}

__global__ void scatter_kernel(const int* __restrict__ src, const int* __restrict__ dst,
                               int* __restrict__ cursor, int* __restrict__ csr_src, int E) {
    int e = blockIdx.x * blockDim.x + threadIdx.x;
    if (e < E) {
        int d = dst[e];
        int pos = atomicAdd(&cursor[d], 1);
        csr_src[pos] = src[e];
    }
}

// ---------------------------------------------------------------------------
// Layer 1 scalar aggregation: z[i] = (1+eps0)*x[i] + sum_{src in N(i)} x[src]
// one wave per node, lanes stride over edges
// ---------------------------------------------------------------------------
__global__ __launch_bounds__(64) void gather1_kernel(const float* __restrict__ x,
                                                     const int* __restrict__ rowptr,
                                                     const int* __restrict__ deg,
                                                     const int* __restrict__ csr_src,
                                                     const float* __restrict__ eps,
                                                     float* __restrict__ zscalar) {
    int node = blockIdx.x;
    int lane = threadIdx.x;
    int start = rowptr[node];
    int cnt = deg[node];
    float a = 0.f;
    for (int i = lane; i < cnt; i += 64) a += x[csr_src[start + i]];
    for (int off = 32; off > 0; off >>= 1) a += __shfl_xor(a, off);
    if (lane == 0) zscalar[node] = (1.0f + eps[0]) * x[node] + a;
}

// ---------------------------------------------------------------------------
// Layers 2-4 vector aggregation fused with z: one wave per node, lane = feature
// z[i][f] = (1+eps)*h[i][f] + sum_{src} h[src][f]
// ---------------------------------------------------------------------------
__global__ __launch_bounds__(64) void gatherz_kernel(const float* __restrict__ hbn,
                                                     const int* __restrict__ rowptr,
                                                     const int* __restrict__ deg,
                                                     const int* __restrict__ csr_src,
                                                     const float* __restrict__ eps,
                                                     int layer,
                                                     float* __restrict__ zbuf) {
    int node = blockIdx.x;
    int lane = threadIdx.x;
    int start = rowptr[node];
    int cnt = deg[node];
    float acc0 = 0.f, acc1 = 0.f, acc2 = 0.f, acc3 = 0.f;
    int e = 0;
    for (; e + 4 <= cnt; e += 4) {
        int s0 = csr_src[start + e + 0];
        int s1 = csr_src[start + e + 1];
        int s2 = csr_src[start + e + 2];
        int s3 = csr_src[start + e + 3];
        acc0 += hbn[s0 * HID + lane];
        acc1 += hbn[s1 * HID + lane];
        acc2 += hbn[s2 * HID + lane];
        acc3 += hbn[s3 * HID + lane];
    }
    for (; e < cnt; ++e) acc0 += hbn[csr_src[start + e] * HID + lane];
    float acc = (acc0 + acc1) + (acc2 + acc3);
    float ep = 1.0f + eps[layer];
    zbuf[node * HID + lane] = ep * hbn[node * HID + lane] + acc;
}

// ---------------------------------------------------------------------------
// MLP tile kernel: 64 nodes per block, 256 threads, 4x4 micro-tiles.
// mode 0 (layer 1): T[n][k] = relu(zscalar[n]*w1a[k] + b1a[k])   (no GEMM1)
// mode 1          : Z staged to LDS, T = relu(Z@W1 + b1)
// then Hpre = relu(T@W2 + b2), written out; per-feature sum/sumsq atomics.
// ---------------------------------------------------------------------------
__global__ __launch_bounds__(256) void mlp_kernel(const float* __restrict__ zin,
                                                  const float* __restrict__ W1,
                                                  const float* __restrict__ b1,
                                                  const float* __restrict__ W2,
                                                  const float* __restrict__ b2,
                                                  float* __restrict__ hpre,
                                                  float* __restrict__ stats,
                                                  int n, int mode) {
    __shared__ float Ws1[HID * HID];
    __shared__ float Ws2[HID * HID];
    __shared__ float Tile[HID * (HID + 1)];  // +1 pad vs bank conflicts

    int tid = threadIdx.x;
    int base = blockIdx.x * 64;

    for (int i = tid; i < HID * HID; i += 256) {
        Ws2[i] = W2[i];
        if (mode) Ws1[i] = W1[i];
    }

    if (mode) {
        for (int idx = tid; idx < 64 * HID; idx += 256) {
            int nn = idx >> 6, k = idx & 63;
            Tile[nn * 65 + k] = zin[(base + nn) * HID + k];
        }
    } else {
        for (int idx = tid; idx < 64 * HID; idx += 256) {
            int nn = idx >> 6, k = idx & 63;
            float zv = zin[base + nn];
            Tile[nn * 65 + k] = fmaxf(fmaf(zv, W1[k], b1[k]), 0.f);
        }
    }
    __syncthreads();

    int r0 = (tid >> 4) * 4;
    int c0 = (tid & 15) * 4;

    float acc[4][4];
#pragma unroll
    for (int i = 0; i < 4; ++i)
#pragma unroll
        for (int j = 0; j < 4; ++j) acc[i][j] = 0.f;

    if (mode) {
        for (int k = 0; k < HID; ++k) {
            float4 w = *(const float4*)&Ws1[k * HID + c0];
#pragma unroll
            for (int i = 0; i < 4; ++i) {
                float a = Tile[(r0 + i) * 65 + k];
                acc[i][0] = fmaf(a, w.x, acc[i][0]);
                acc[i][1] = fmaf(a, w.y, acc[i][1]);
                acc[i][2] = fmaf(a, w.z, acc[i][2]);
                acc[i][3] = fmaf(a, w.w, acc[i][3]);
            }
        }
        __syncthreads();
#pragma unroll
        for (int i = 0; i < 4; ++i)
#pragma unroll
            for (int j = 0; j < 4; ++j)
                Tile[(r0 + i) * 65 + c0 + j] = fmaxf(acc[i][j] + b1[c0 + j], 0.f);
#pragma unroll
        for (int i = 0; i < 4; ++i)
#pragma unroll
            for (int j = 0; j < 4; ++j) acc[i][j] = 0.f;
        __syncthreads();
    }

    // GEMM2: Hpre = relu(T @ W2 + b2)
    for (int k = 0; k < HID; ++k) {
        float4 w = *(const float4*)&Ws2[k * HID + c0];
#pragma unroll
        for (int i = 0; i < 4; ++i) {
            float a = Tile[(r0 + i) * 65 + k];
            acc[i][0] = fmaf(a, w.x, acc[i][0]);
            acc[i][1] = fmaf(a, w.y, acc[i][1]);
            acc[i][2] = fmaf(a, w.z, acc[i][2]);
            acc[i][3] = fmaf(a, w.w, acc[i][3]);
        }
    }

    float hv[4][4];
#pragma unroll
    for (int i = 0; i < 4; ++i)
#pragma unroll
        for (int j = 0; j < 4; ++j) hv[i][j] = fmaxf(acc[i][j] + b2[c0 + j], 0.f);

    __syncthreads();  // GEMM2 done reading Tile
#pragma unroll
    for (int i = 0; i < 4; ++i)
#pragma unroll
        for (int j = 0; j < 4; ++j) Tile[(r0 + i) * 65 + c0 + j] = hv[i][j];
    __syncthreads();

    // store valid rows
#pragma unroll
    for (int i = 0; i < 4; ++i) {
        int node = base + r0 + i;
        if (node < n) {
            float4 o = make_float4(hv[i][0], hv[i][1], hv[i][2], hv[i][3]);
            *(float4*)&hpre[node * HID + c0] = o;
        }
    }

    // per-feature stats over valid rows of this tile
    if (tid < 64) {
        int lim = n - base; if (lim > 64) lim = 64;
        float s = 0.f, s2 = 0.f;
        for (int r = 0; r < lim; ++r) {
            float v = Tile[r * 65 + tid];
            s += v;
            s2 = fmaf(v, v, s2);
        }
        atomicAdd(&stats[tid], s);
        atomicAdd(&stats[64 + tid], s2);
    }
}

// ---------------------------------------------------------------------------
// BN finalize: scale/shift per feature
// ---------------------------------------------------------------------------
__global__ __launch_bounds__(64) void bnfin_kernel(const float* __restrict__ stats,
                                                   const float* __restrict__ gamma,
                                                   const float* __restrict__ beta,
                                                   float* __restrict__ bnp, int n) {
    int f = threadIdx.x;
    float inv_n = 1.0f / (float)n;
    float mu = stats[f] * inv_n;
    float var = stats[64 + f] * inv_n - mu * mu;
    float inv = rsqrtf(var + BN_EPS);
    float sc = gamma[f] * inv;
    float sh = beta[f] - mu * sc;
    bnp[f] = sc;
    bnp[64 + f] = sh;
}

// ---------------------------------------------------------------------------
// BN apply (layers 1-3): hbn = hpre*scale + shift, float4 vectorized
// ---------------------------------------------------------------------------
__global__ __launch_bounds__(256) void bnapply_kernel(const float* __restrict__ hpre,
                                                      const float* __restrict__ bnp,
                                                      float* __restrict__ hbn, int n4) {
    int i = blockIdx.x * blockDim.x + threadIdx.x;
    if (i < n4) {
        float4 v = ((const float4*)hpre)[i];
        int f4 = i & 15;
        float4 sc = ((const float4*)bnp)[f4];
        float4 sh = ((const float4*)(bnp + 64))[f4];
        float4 r;
        r.x = fmaf(v.x, sc.x, sh.x);
        r.y = fmaf(v.y, sc.y, sh.y);
        r.z = fmaf(v.z, sc.z, sh.z);
        r.w = fmaf(v.w, sc.w, sh.w);
        ((float4*)hbn)[i] = r;
    }
}

// ---------------------------------------------------------------------------
// Final: out[i] = sum_f (hpre[i][f]*sc[f]+sh[f]) * fcw[f] + fcb
// one wave per node
// ---------------------------------------------------------------------------
__global__ __launch_bounds__(256) void final_kernel(const float* __restrict__ hpre,
                                                    const float* __restrict__ bnp,
                                                    const float* __restrict__ fcw,
                                                    const float* __restrict__ fcb,
                                                    float* __restrict__ out, int n) {
    int wave = threadIdx.x >> 6;
    int lane = threadIdx.x & 63;
    int node = blockIdx.x * 4 + wave;
    if (node < n) {
        float v = hpre[node * HID + lane];
        float t = fmaf(v, bnp[lane], bnp[64 + lane]) * fcw[lane];
        for (int off = 32; off > 0; off >>= 1) t += __shfl_xor(t, off);
        if (lane == 0) out[node] = t + fcb[0];
    }
}

// ---------------------------------------------------------------------------
extern "C" void kernel_launch(void* const* d_in, const int* in_sizes, int n_in,
                              void* d_out, int out_size, void* d_ws, size_t ws_size,
                              hipStream_t stream) {
    const float* x      = (const float*)d_in[0];
    const int*   ei     = (const int*)d_in[1];
    const float* w1a    = (const float*)d_in[2];
    const float* b1a    = (const float*)d_in[3];
    const float* w2a    = (const float*)d_in[4];
    const float* b2a    = (const float*)d_in[5];
    const float* w1s    = (const float*)d_in[6];
    const float* b1s    = (const float*)d_in[7];
    const float* w2s    = (const float*)d_in[8];
    const float* b2s    = (const float*)d_in[9];
    const float* eps    = (const float*)d_in[10];
    const float* gammas = (const float*)d_in[11];
    const float* betas  = (const float*)d_in[12];
    const float* fcw    = (const float*)d_in[13];
    const float* fcb    = (const float*)d_in[14];
    float* out = (float*)d_out;

    int n = in_sizes[0];          // 50000
    int E = in_sizes[1] / 2;      // 1600000
    int npad = ((n + 63) / 64) * 64;
    int nblk = npad / 64;

    const int* src = ei;
    const int* dst = ei + E;

    char* p = (char*)d_ws;
    float* zbuf    = (float*)p; p += (size_t)npad * HID * 4;
    float* hpre    = (float*)p; p += (size_t)npad * HID * 4;
    float* hbn     = (float*)p; p += (size_t)npad * HID * 4;
    float* zscalar = (float*)p; p += (size_t)npad * 4;
    float* stats   = (float*)p; p += 4 * 128 * 4;   // [layer][sum(64), sumsq(64)]
    float* bnp     = (float*)p; p += 4 * 128 * 4;   // [layer][scale(64), shift(64)]
    int* deg     = (int*)p; p += (size_t)n * 4;
    int* rowptr  = (int*)p; p += (size_t)n * 4;
    int* cursor  = (int*)p; p += (size_t)n * 4;
    int* csr_src = (int*)p; p += (size_t)E * 4;

    hipMemsetAsync(deg, 0, (size_t)n * 4, stream);
    hipMemsetAsync(stats, 0, 4 * 128 * 4, stream);

    // CSR build
    hist_kernel<<<(E + 255) / 256, 256, 0, stream>>>(dst, deg, E);
    scan_kernel<<<1, 1024, 0, stream>>>(deg, rowptr, cursor, n);
    scatter_kernel<<<(E + 255) / 256, 256, 0, stream>>>(src, dst, cursor, csr_src, E);

    // ---- Layer 1 (1 -> 64 -> 64) ----
    gather1_kernel<<<n, 64, 0, stream>>>(x, rowptr, deg, csr_src, eps, zscalar);
    mlp_kernel<<<nblk, 256, 0, stream>>>(zscalar, w1a, b1a, w2a, b2a, hpre, stats, n, 0);
    bnfin_kernel<<<1, 64, 0, stream>>>(stats, gammas, betas, bnp, n);
    bnapply_kernel<<<(n * HID / 4 + 255) / 256, 256, 0, stream>>>(hpre, bnp, hbn, n * HID / 4);

    // ---- Layers 2-4 ----
    for (int l = 1; l <= 3; ++l) {
        gatherz_kernel<<<n, 64, 0, stream>>>(hbn, rowptr, deg, csr_src, eps, l, zbuf);
        mlp_kernel<<<nblk, 256, 0, stream>>>(zbuf,
                                             w1s + (size_t)(l - 1) * HID * HID,
                                             b1s + (size_t)(l - 1) * HID,
                                             w2s + (size_t)(l - 1) * HID * HID,
                                             b2s + (size_t)(l - 1) * HID,
                                             hpre, stats + l * 128, n, 1);
        bnfin_kernel<<<1, 64, 0, stream>>>(stats + l * 128, gammas + l * HID,
                                           betas + l * HID, bnp + l * 128, n);
        if (l < 3) {
            bnapply_kernel<<<(n * HID / 4 + 255) / 256, 256, 0, stream>>>(
                hpre, bnp + l * 128, hbn, n * HID / 4);
        } else {
            final_kernel<<<(n + 3) / 4, 256, 0, stream>>>(hpre, bnp + 3 * 128, fcw, fcb, out, n);
        }
    }
}

// Round 2
// 723.778 us; speedup vs baseline: 1.0663x; 1.0663x over previous
//
#include <hip/hip_runtime.h>

#define HID 64
#define BN_EPS 1e-5f
#define NWIN 8

// ---------------------------------------------------------------------------
// CSR build: histogram -> single-block scan -> windowed scatter
// ---------------------------------------------------------------------------
__global__ void hist_kernel(const int* __restrict__ dst, int* __restrict__ deg, int E) {
    int e = blockIdx.x * blockDim.x + threadIdx.x;
    if (e < E) atomicAdd(&deg[dst[e]], 1);
}

__global__ __launch_bounds__(1024) void scan_kernel(const int* __restrict__ deg,
                                                    int* __restrict__ rowptr,
                                                    int* __restrict__ cursor, int n) {
    __shared__ int sums[1024];
    int tid = threadIdx.x;
    int ch = (n + 1023) / 1024;
    int begin = tid * ch;
    int end = begin + ch; if (end > n) end = n;
    int s = 0;
    for (int i = begin; i < end; ++i) s += deg[i];
    sums[tid] = s;
    __syncthreads();
    for (int off = 1; off < 1024; off <<= 1) {
        int v = (tid >= off) ? sums[tid - off] : 0;
        __syncthreads();
        sums[tid] += v;
        __syncthreads();
    }
    int run = (tid == 0) ? 0 : sums[tid - 1];
    for (int i = begin; i < end; ++i) {
        rowptr[i] = run; cursor[i] = run;
        run += deg[i];
    }
}

// Window-confined scatter: only edges with dst in [lo,hi) are placed.
// Live write region per pass ~E/NWIN*4B = 800 KB -> should stay L2-resident
// so partial-line stores merge before writeback.
__global__ void scatter_win_kernel(const int* __restrict__ src, const int* __restrict__ dst,
                                   int* __restrict__ cursor, int* __restrict__ csr_src,
                                   int E, int lo, int hi) {
    int e = blockIdx.x * blockDim.x + threadIdx.x;
    if (e < E) {
        int d = dst[e];
        if (d >= lo && d < hi) {
            int pos = atomicAdd(&cursor[d], 1);
            csr_src[pos] = src[e];
        }
    }
}

// ---------------------------------------------------------------------------
// Layer 1 scalar aggregation: z[i] = (1+eps0)*x[i] + sum_{src in N(i)} x[src]
// 4 waves per block, one wave per node, lanes stride over edges
// ---------------------------------------------------------------------------
__global__ __launch_bounds__(256) void gather1_kernel(const float* __restrict__ x,
                                                      const int* __restrict__ rowptr,
                                                      const int* __restrict__ deg,
                                                      const int* __restrict__ csr_src,
                                                      const float* __restrict__ eps,
                                                      float* __restrict__ zscalar, int n) {
    int node = blockIdx.x * 4 + (threadIdx.x >> 6);
    int lane = threadIdx.x & 63;
    if (node >= n) return;
    int start = __builtin_amdgcn_readfirstlane(rowptr[node]);
    int cnt   = __builtin_amdgcn_readfirstlane(deg[node]);
    float a = 0.f;
    for (int i = lane; i < cnt; i += 64) a += x[csr_src[start + i]];
    for (int off = 32; off > 0; off >>= 1) a += __shfl_xor(a, off);
    if (lane == 0) zscalar[node] = (1.0f + eps[0]) * x[node] + a;
}

// ---------------------------------------------------------------------------
// Layers 2-4 aggregation with BN of the PREVIOUS layer folded in:
//   hbn = sc*hp + sh   (per-feature affine)
//   z   = ep*hbn_i + sum_s hbn_s = sc*(ep*hp_i + sum_s hp_s) + sh*(ep + deg)
// one wave per node, lane = feature, 8-deep unroll
// ---------------------------------------------------------------------------
__global__ __launch_bounds__(256) void gatherz_kernel(const float* __restrict__ hpre,
                                                      const float* __restrict__ bnp,
                                                      const int* __restrict__ rowptr,
                                                      const int* __restrict__ deg,
                                                      const int* __restrict__ csr_src,
                                                      const float* __restrict__ eps,
                                                      int layer,
                                                      float* __restrict__ zbuf, int n) {
    int node = blockIdx.x * 4 + (threadIdx.x >> 6);
    int lane = threadIdx.x & 63;
    if (node >= n) return;
    int start = __builtin_amdgcn_readfirstlane(rowptr[node]);
    int cnt   = __builtin_amdgcn_readfirstlane(deg[node]);
    float a0 = 0.f, a1 = 0.f, a2 = 0.f, a3 = 0.f;
    float a4 = 0.f, a5 = 0.f, a6 = 0.f, a7 = 0.f;
    int e = 0;
    for (; e + 8 <= cnt; e += 8) {
        int s0 = csr_src[start + e + 0];
        int s1 = csr_src[start + e + 1];
        int s2 = csr_src[start + e + 2];
        int s3 = csr_src[start + e + 3];
        int s4 = csr_src[start + e + 4];
        int s5 = csr_src[start + e + 5];
        int s6 = csr_src[start + e + 6];
        int s7 = csr_src[start + e + 7];
        a0 += hpre[(size_t)s0 * HID + lane];
        a1 += hpre[(size_t)s1 * HID + lane];
        a2 += hpre[(size_t)s2 * HID + lane];
        a3 += hpre[(size_t)s3 * HID + lane];
        a4 += hpre[(size_t)s4 * HID + lane];
        a5 += hpre[(size_t)s5 * HID + lane];
        a6 += hpre[(size_t)s6 * HID + lane];
        a7 += hpre[(size_t)s7 * HID + lane];
    }
    for (; e < cnt; ++e) a0 += hpre[(size_t)csr_src[start + e] * HID + lane];
    float sum = ((a0 + a1) + (a2 + a3)) + ((a4 + a5) + (a6 + a7));
    float ep = 1.0f + eps[layer];
    float sc = bnp[lane], sh = bnp[64 + lane];
    float self = hpre[(size_t)node * HID + lane];
    zbuf[(size_t)node * HID + lane] =
        fmaf(sc, fmaf(ep, self, sum), sh * (ep + (float)cnt));
}

// ---------------------------------------------------------------------------
// MLP tile kernel: 64 nodes per block, 256 threads, 4x4 micro-tiles.
// mode 0 (layer 1): T[n][k] = relu(zscalar[n]*w1a[k] + b1a[k])   (no GEMM1)
// mode 1          : Z staged to LDS, T = relu(Z@W1 + b1)
// then Hpre = relu(T@W2 + b2), written out; per-feature sum/sumsq atomics.
// ---------------------------------------------------------------------------
__global__ __launch_bounds__(256) void mlp_kernel(const float* __restrict__ zin,
                                                  const float* __restrict__ W1,
                                                  const float* __restrict__ b1,
                                                  const float* __restrict__ W2,
                                                  const float* __restrict__ b2,
                                                  float* __restrict__ hpre,
                                                  float* __restrict__ stats,
                                                  int n, int mode) {
    __shared__ float Ws1[HID * HID];
    __shared__ float Ws2[HID * HID];
    __shared__ float Tile[HID * (HID + 1)];  // +1 pad vs bank conflicts

    int tid = threadIdx.x;
    int base = blockIdx.x * 64;

    for (int i = tid; i < HID * HID; i += 256) {
        Ws2[i] = W2[i];
        if (mode) Ws1[i] = W1[i];
    }

    if (mode) {
        for (int idx = tid; idx < 64 * HID; idx += 256) {
            int nn = idx >> 6, k = idx & 63;
            Tile[nn * 65 + k] = zin[(base + nn) * HID + k];
        }
    } else {
        for (int idx = tid; idx < 64 * HID; idx += 256) {
            int nn = idx >> 6, k = idx & 63;
            float zv = zin[base + nn];
            Tile[nn * 65 + k] = fmaxf(fmaf(zv, W1[k], b1[k]), 0.f);
        }
    }
    __syncthreads();

    int r0 = (tid >> 4) * 4;
    int c0 = (tid & 15) * 4;

    float acc[4][4];
#pragma unroll
    for (int i = 0; i < 4; ++i)
#pragma unroll
        for (int j = 0; j < 4; ++j) acc[i][j] = 0.f;

    if (mode) {
        for (int k = 0; k < HID; ++k) {
            float4 w = *(const float4*)&Ws1[k * HID + c0];
#pragma unroll
            for (int i = 0; i < 4; ++i) {
                float a = Tile[(r0 + i) * 65 + k];
                acc[i][0] = fmaf(a, w.x, acc[i][0]);
                acc[i][1] = fmaf(a, w.y, acc[i][1]);
                acc[i][2] = fmaf(a, w.z, acc[i][2]);
                acc[i][3] = fmaf(a, w.w, acc[i][3]);
            }
        }
        __syncthreads();
#pragma unroll
        for (int i = 0; i < 4; ++i)
#pragma unroll
            for (int j = 0; j < 4; ++j)
                Tile[(r0 + i) * 65 + c0 + j] = fmaxf(acc[i][j] + b1[c0 + j], 0.f);
#pragma unroll
        for (int i = 0; i < 4; ++i)
#pragma unroll
            for (int j = 0; j < 4; ++j) acc[i][j] = 0.f;
        __syncthreads();
    }

    // GEMM2: Hpre = relu(T @ W2 + b2)
    for (int k = 0; k < HID; ++k) {
        float4 w = *(const float4*)&Ws2[k * HID + c0];
#pragma unroll
        for (int i = 0; i < 4; ++i) {
            float a = Tile[(r0 + i) * 65 + k];
            acc[i][0] = fmaf(a, w.x, acc[i][0]);
            acc[i][1] = fmaf(a, w.y, acc[i][1]);
            acc[i][2] = fmaf(a, w.z, acc[i][2]);
            acc[i][3] = fmaf(a, w.w, acc[i][3]);
        }
    }

    float hv[4][4];
#pragma unroll
    for (int i = 0; i < 4; ++i)
#pragma unroll
        for (int j = 0; j < 4; ++j) hv[i][j] = fmaxf(acc[i][j] + b2[c0 + j], 0.f);

    __syncthreads();  // GEMM2 done reading Tile
#pragma unroll
    for (int i = 0; i < 4; ++i)
#pragma unroll
        for (int j = 0; j < 4; ++j) Tile[(r0 + i) * 65 + c0 + j] = hv[i][j];
    __syncthreads();

    // store valid rows
#pragma unroll
    for (int i = 0; i < 4; ++i) {
        int node = base + r0 + i;
        if (node < n) {
            float4 o = make_float4(hv[i][0], hv[i][1], hv[i][2], hv[i][3]);
            *(float4*)&hpre[node * HID + c0] = o;
        }
    }

    // per-feature stats over valid rows of this tile
    if (tid < 64) {
        int lim = n - base; if (lim > 64) lim = 64;
        float s = 0.f, s2 = 0.f;
        for (int r = 0; r < lim; ++r) {
            float v = Tile[r * 65 + tid];
            s += v;
            s2 = fmaf(v, v, s2);
        }
        atomicAdd(&stats[tid], s);
        atomicAdd(&stats[64 + tid], s2);
    }
}

// ---------------------------------------------------------------------------
// BN finalize: scale/shift per feature
// ---------------------------------------------------------------------------
__global__ __launch_bounds__(64) void bnfin_kernel(const float* __restrict__ stats,
                                                   const float* __restrict__ gamma,
                                                   const float* __restrict__ beta,
                                                   float* __restrict__ bnp, int n) {
    int f = threadIdx.x;
    float inv_n = 1.0f / (float)n;
    float mu = stats[f] * inv_n;
    float var = stats[64 + f] * inv_n - mu * mu;
    float inv = rsqrtf(var + BN_EPS);
    float sc = gamma[f] * inv;
    float sh = beta[f] - mu * sc;
    bnp[f] = sc;
    bnp[64 + f] = sh;
}

// ---------------------------------------------------------------------------
// Final: out[i] = sum_f (hpre[i][f]*sc[f]+sh[f]) * fcw[f] + fcb
// ---------------------------------------------------------------------------
__global__ __launch_bounds__(256) void final_kernel(const float* __restrict__ hpre,
                                                    const float* __restrict__ bnp,
                                                    const float* __restrict__ fcw,
                                                    const float* __restrict__ fcb,
                                                    float* __restrict__ out, int n) {
    int wave = threadIdx.x >> 6;
    int lane = threadIdx.x & 63;
    int node = blockIdx.x * 4 + wave;
    if (node < n) {
        float v = hpre[(size_t)node * HID + lane];
        float t = fmaf(v, bnp[lane], bnp[64 + lane]) * fcw[lane];
        for (int off = 32; off > 0; off >>= 1) t += __shfl_xor(t, off);
        if (lane == 0) out[node] = t + fcb[0];
    }
}

// ---------------------------------------------------------------------------
extern "C" void kernel_launch(void* const* d_in, const int* in_sizes, int n_in,
                              void* d_out, int out_size, void* d_ws, size_t ws_size,
                              hipStream_t stream) {
    const float* x      = (const float*)d_in[0];
    const int*   ei     = (const int*)d_in[1];
    const float* w1a    = (const float*)d_in[2];
    const float* b1a    = (const float*)d_in[3];
    const float* w2a    = (const float*)d_in[4];
    const float* b2a    = (const float*)d_in[5];
    const float* w1s    = (const float*)d_in[6];
    const float* b1s    = (const float*)d_in[7];
    const float* w2s    = (const float*)d_in[8];
    const float* b2s    = (const float*)d_in[9];
    const float* eps    = (const float*)d_in[10];
    const float* gammas = (const float*)d_in[11];
    const float* betas  = (const float*)d_in[12];
    const float* fcw    = (const float*)d_in[13];
    const float* fcb    = (const float*)d_in[14];
    float* out = (float*)d_out;

    int n = in_sizes[0];          // 50000
    int E = in_sizes[1] / 2;      // 1600000
    int npad = ((n + 63) / 64) * 64;
    int nblk = npad / 64;

    const int* src = ei;
    const int* dst = ei + E;

    char* p = (char*)d_ws;
    float* zbuf    = (float*)p; p += (size_t)npad * HID * 4;
    float* hpre    = (float*)p; p += (size_t)npad * HID * 4;
    float* zscalar = (float*)p; p += (size_t)npad * 4;
    float* stats   = (float*)p; p += 4 * 128 * 4;   // [layer][sum(64), sumsq(64)]
    float* bnp     = (float*)p; p += 4 * 128 * 4;   // [layer][scale(64), shift(64)]
    int* deg     = (int*)p; p += (size_t)n * 4;
    int* rowptr  = (int*)p; p += (size_t)n * 4;
    int* cursor  = (int*)p; p += (size_t)n * 4;
    int* csr_src = (int*)p; p += (size_t)E * 4;

    hipMemsetAsync(deg, 0, (size_t)n * 4, stream);
    hipMemsetAsync(stats, 0, 4 * 128 * 4, stream);

    // CSR build
    hist_kernel<<<(E + 255) / 256, 256, 0, stream>>>(dst, deg, E);
    scan_kernel<<<1, 1024, 0, stream>>>(deg, rowptr, cursor, n);
    int wsz = (n + NWIN - 1) / NWIN;
    for (int w = 0; w < NWIN; ++w) {
        int lo = w * wsz;
        int hi = lo + wsz; if (hi > n) hi = n;
        scatter_win_kernel<<<(E + 255) / 256, 256, 0, stream>>>(src, dst, cursor, csr_src,
                                                                E, lo, hi);
    }

    // ---- Layer 1 (1 -> 64 -> 64) ----
    gather1_kernel<<<(n + 3) / 4, 256, 0, stream>>>(x, rowptr, deg, csr_src, eps, zscalar, n);
    mlp_kernel<<<nblk, 256, 0, stream>>>(zscalar, w1a, b1a, w2a, b2a, hpre, stats, n, 0);
    bnfin_kernel<<<1, 64, 0, stream>>>(stats, gammas, betas, bnp, n);

    // ---- Layers 2-4 (BN of previous layer folded into gatherz) ----
    for (int l = 1; l <= 3; ++l) {
        gatherz_kernel<<<(n + 3) / 4, 256, 0, stream>>>(hpre, bnp + (l - 1) * 128,
                                                        rowptr, deg, csr_src, eps, l, zbuf, n);
        mlp_kernel<<<nblk, 256, 0, stream>>>(zbuf,
                                             w1s + (size_t)(l - 1) * HID * HID,
                                             b1s + (size_t)(l - 1) * HID,
                                             w2s + (size_t)(l - 1) * HID * HID,
                                             b2s + (size_t)(l - 1) * HID,
                                             hpre, stats + l * 128, n, 1);
        bnfin_kernel<<<1, 64, 0, stream>>>(stats + l * 128, gammas + l * HID,
                                           betas + l * HID, bnp + l * 128, n);
    }
    final_kernel<<<(n + 3) / 4, 256, 0, stream>>>(hpre, bnp + 3 * 128, fcw, fcb, out, n);
}

// Round 3
// 623.046 us; speedup vs baseline: 1.2387x; 1.1617x over previous
//
#include <hip/hip_runtime.h>

#define HID 64
#define BN_EPS 1e-5f
#define NWIN 8

// ---------------------------------------------------------------------------
// CSR build: histogram -> 3-stage hierarchical scan -> windowed scatter
// ---------------------------------------------------------------------------
__global__ void hist_kernel(const int* __restrict__ dst, int* __restrict__ deg, int E) {
    int e = blockIdx.x * blockDim.x + threadIdx.x;
    if (e < E) atomicAdd(&deg[dst[e]], 1);
}

// Stage A: per-block inclusive scan of deg (256 nodes/block).
// partial[i] = exclusive prefix within block; blocksum[b] = block total.
__global__ __launch_bounds__(256) void scan_a_kernel(const int* __restrict__ deg,
                                                     int* __restrict__ partial,
                                                     int* __restrict__ blocksum, int n) {
    __shared__ int sums[256];
    int tid = threadIdx.x;
    int i = blockIdx.x * 256 + tid;
    int v = (i < n) ? deg[i] : 0;
    sums[tid] = v;
    __syncthreads();
    for (int off = 1; off < 256; off <<= 1) {
        int t = (tid >= off) ? sums[tid - off] : 0;
        __syncthreads();
        sums[tid] += t;
        __syncthreads();
    }
    if (i < n) partial[i] = sums[tid] - v;      // exclusive
    if (tid == 255) blocksum[blockIdx.x] = sums[255];
}

// Stage B: single-block exclusive scan of blocksums (carry loop, generic nb).
__global__ __launch_bounds__(256) void scan_b_kernel(const int* __restrict__ blocksum,
                                                     int* __restrict__ blockoff, int nb) {
    __shared__ int s[256];
    __shared__ int carry;
    int tid = threadIdx.x;
    if (tid == 0) carry = 0;
    __syncthreads();
    for (int base = 0; base < nb; base += 256) {
        int i = base + tid;
        int v = (i < nb) ? blocksum[i] : 0;
        s[tid] = v;
        __syncthreads();
        for (int off = 1; off < 256; off <<= 1) {
            int t = (tid >= off) ? s[tid - off] : 0;
            __syncthreads();
            s[tid] += t;
            __syncthreads();
        }
        if (i < nb) blockoff[i] = carry + s[tid] - v;   // exclusive
        __syncthreads();
        if (tid == 0) carry += s[255];
        __syncthreads();
    }
}

// Stage C: rowptr[i] = cursor[i] = partial[i] + blockoff[block(i)]
__global__ __launch_bounds__(256) void scan_c_kernel(const int* __restrict__ partial,
                                                     const int* __restrict__ blockoff,
                                                     int* __restrict__ rowptr,
                                                     int* __restrict__ cursor, int n) {
    int i = blockIdx.x * 256 + threadIdx.x;
    if (i < n) {
        int r = partial[i] + blockoff[blockIdx.x];
        rowptr[i] = r;
        cursor[i] = r;
    }
}

// Window-confined scatter: only edges with dst in [lo,hi) are placed.
// Live write region per pass ~E/NWIN*4B = 800 KB -> stays L2-resident
// so partial-line stores merge before writeback.
__global__ void scatter_win_kernel(const int* __restrict__ src, const int* __restrict__ dst,
                                   int* __restrict__ cursor, int* __restrict__ csr_src,
                                   int E, int lo, int hi) {
    int e = blockIdx.x * blockDim.x + threadIdx.x;
    if (e < E) {
        int d = dst[e];
        if (d >= lo && d < hi) {
            int pos = atomicAdd(&cursor[d], 1);
            csr_src[pos] = src[e];
        }
    }
}

// ---------------------------------------------------------------------------
// Layer 1 scalar aggregation: z[i] = (1+eps0)*x[i] + sum_{src in N(i)} x[src]
// ---------------------------------------------------------------------------
__global__ __launch_bounds__(256) void gather1_kernel(const float* __restrict__ x,
                                                      const int* __restrict__ rowptr,
                                                      const int* __restrict__ deg,
                                                      const int* __restrict__ csr_src,
                                                      const float* __restrict__ eps,
                                                      float* __restrict__ zscalar, int n) {
    int node = blockIdx.x * 4 + (threadIdx.x >> 6);
    int lane = threadIdx.x & 63;
    if (node >= n) return;
    int start = __builtin_amdgcn_readfirstlane(rowptr[node]);
    int cnt   = __builtin_amdgcn_readfirstlane(deg[node]);
    float a = 0.f;
    for (int i = lane; i < cnt; i += 64) a += x[csr_src[start + i]];
    for (int off = 32; off > 0; off >>= 1) a += __shfl_xor(a, off);
    if (lane == 0) zscalar[node] = (1.0f + eps[0]) * x[node] + a;
}

// ---------------------------------------------------------------------------
// Layers 2-4 aggregation with BN of the PREVIOUS layer folded in:
//   z = sc*(ep*hp_i + sum_s hp_s) + sh*(ep + deg)
// ---------------------------------------------------------------------------
__global__ __launch_bounds__(256) void gatherz_kernel(const float* __restrict__ hpre,
                                                      const float* __restrict__ bnp,
                                                      const int* __restrict__ rowptr,
                                                      const int* __restrict__ deg,
                                                      const int* __restrict__ csr_src,
                                                      const float* __restrict__ eps,
                                                      int layer,
                                                      float* __restrict__ zbuf, int n) {
    int node = blockIdx.x * 4 + (threadIdx.x >> 6);
    int lane = threadIdx.x & 63;
    if (node >= n) return;
    int start = __builtin_amdgcn_readfirstlane(rowptr[node]);
    int cnt   = __builtin_amdgcn_readfirstlane(deg[node]);
    float a0 = 0.f, a1 = 0.f, a2 = 0.f, a3 = 0.f;
    float a4 = 0.f, a5 = 0.f, a6 = 0.f, a7 = 0.f;
    int e = 0;
    for (; e + 8 <= cnt; e += 8) {
        int s0 = csr_src[start + e + 0];
        int s1 = csr_src[start + e + 1];
        int s2 = csr_src[start + e + 2];
        int s3 = csr_src[start + e + 3];
        int s4 = csr_src[start + e + 4];
        int s5 = csr_src[start + e + 5];
        int s6 = csr_src[start + e + 6];
        int s7 = csr_src[start + e + 7];
        a0 += hpre[(size_t)s0 * HID + lane];
        a1 += hpre[(size_t)s1 * HID + lane];
        a2 += hpre[(size_t)s2 * HID + lane];
        a3 += hpre[(size_t)s3 * HID + lane];
        a4 += hpre[(size_t)s4 * HID + lane];
        a5 += hpre[(size_t)s5 * HID + lane];
        a6 += hpre[(size_t)s6 * HID + lane];
        a7 += hpre[(size_t)s7 * HID + lane];
    }
    for (; e < cnt; ++e) a0 += hpre[(size_t)csr_src[start + e] * HID + lane];
    float sum = ((a0 + a1) + (a2 + a3)) + ((a4 + a5) + (a6 + a7));
    float ep = 1.0f + eps[layer];
    float sc = bnp[lane], sh = bnp[64 + lane];
    float self = hpre[(size_t)node * HID + lane];
    zbuf[(size_t)node * HID + lane] =
        fmaf(sc, fmaf(ep, self, sum), sh * (ep + (float)cnt));
}

// ---------------------------------------------------------------------------
// MLP tile kernel: 64 nodes per block, 256 threads, 4x4 micro-tiles.
// ---------------------------------------------------------------------------
__global__ __launch_bounds__(256) void mlp_kernel(const float* __restrict__ zin,
                                                  const float* __restrict__ W1,
                                                  const float* __restrict__ b1,
                                                  const float* __restrict__ W2,
                                                  const float* __restrict__ b2,
                                                  float* __restrict__ hpre,
                                                  float* __restrict__ stats,
                                                  int n, int mode) {
    __shared__ float Ws1[HID * HID];
    __shared__ float Ws2[HID * HID];
    __shared__ float Tile[HID * (HID + 1)];  // +1 pad vs bank conflicts

    int tid = threadIdx.x;
    int base = blockIdx.x * 64;

    for (int i = tid; i < HID * HID; i += 256) {
        Ws2[i] = W2[i];
        if (mode) Ws1[i] = W1[i];
    }

    if (mode) {
        for (int idx = tid; idx < 64 * HID; idx += 256) {
            int nn = idx >> 6, k = idx & 63;
            Tile[nn * 65 + k] = zin[(base + nn) * HID + k];
        }
    } else {
        for (int idx = tid; idx < 64 * HID; idx += 256) {
            int nn = idx >> 6, k = idx & 63;
            float zv = zin[base + nn];
            Tile[nn * 65 + k] = fmaxf(fmaf(zv, W1[k], b1[k]), 0.f);
        }
    }
    __syncthreads();

    int r0 = (tid >> 4) * 4;
    int c0 = (tid & 15) * 4;

    float acc[4][4];
#pragma unroll
    for (int i = 0; i < 4; ++i)
#pragma unroll
        for (int j = 0; j < 4; ++j) acc[i][j] = 0.f;

    if (mode) {
        for (int k = 0; k < HID; ++k) {
            float4 w = *(const float4*)&Ws1[k * HID + c0];
#pragma unroll
            for (int i = 0; i < 4; ++i) {
                float a = Tile[(r0 + i) * 65 + k];
                acc[i][0] = fmaf(a, w.x, acc[i][0]);
                acc[i][1] = fmaf(a, w.y, acc[i][1]);
                acc[i][2] = fmaf(a, w.z, acc[i][2]);
                acc[i][3] = fmaf(a, w.w, acc[i][3]);
            }
        }
        __syncthreads();
#pragma unroll
        for (int i = 0; i < 4; ++i)
#pragma unroll
            for (int j = 0; j < 4; ++j)
                Tile[(r0 + i) * 65 + c0 + j] = fmaxf(acc[i][j] + b1[c0 + j], 0.f);
#pragma unroll
        for (int i = 0; i < 4; ++i)
#pragma unroll
            for (int j = 0; j < 4; ++j) acc[i][j] = 0.f;
        __syncthreads();
    }

    // GEMM2: Hpre = relu(T @ W2 + b2)
    for (int k = 0; k < HID; ++k) {
        float4 w = *(const float4*)&Ws2[k * HID + c0];
#pragma unroll
        for (int i = 0; i < 4; ++i) {
            float a = Tile[(r0 + i) * 65 + k];
            acc[i][0] = fmaf(a, w.x, acc[i][0]);
            acc[i][1] = fmaf(a, w.y, acc[i][1]);
            acc[i][2] = fmaf(a, w.z, acc[i][2]);
            acc[i][3] = fmaf(a, w.w, acc[i][3]);
        }
    }

    float hv[4][4];
#pragma unroll
    for (int i = 0; i < 4; ++i)
#pragma unroll
        for (int j = 0; j < 4; ++j) hv[i][j] = fmaxf(acc[i][j] + b2[c0 + j], 0.f);

    __syncthreads();  // GEMM2 done reading Tile
#pragma unroll
    for (int i = 0; i < 4; ++i)
#pragma unroll
        for (int j = 0; j < 4; ++j) Tile[(r0 + i) * 65 + c0 + j] = hv[i][j];
    __syncthreads();

    // store valid rows
#pragma unroll
    for (int i = 0; i < 4; ++i) {
        int node = base + r0 + i;
        if (node < n) {
            float4 o = make_float4(hv[i][0], hv[i][1], hv[i][2], hv[i][3]);
            *(float4*)&hpre[node * HID + c0] = o;
        }
    }

    // per-feature stats over valid rows of this tile
    if (tid < 64) {
        int lim = n - base; if (lim > 64) lim = 64;
        float s = 0.f, s2 = 0.f;
        for (int r = 0; r < lim; ++r) {
            float v = Tile[r * 65 + tid];
            s += v;
            s2 = fmaf(v, v, s2);
        }
        atomicAdd(&stats[tid], s);
        atomicAdd(&stats[64 + tid], s2);
    }
}

// ---------------------------------------------------------------------------
// BN finalize: scale/shift per feature
// ---------------------------------------------------------------------------
__global__ __launch_bounds__(64) void bnfin_kernel(const float* __restrict__ stats,
                                                   const float* __restrict__ gamma,
                                                   const float* __restrict__ beta,
                                                   float* __restrict__ bnp, int n) {
    int f = threadIdx.x;
    float inv_n = 1.0f / (float)n;
    float mu = stats[f] * inv_n;
    float var = stats[64 + f] * inv_n - mu * mu;
    float inv = rsqrtf(var + BN_EPS);
    float sc = gamma[f] * inv;
    float sh = beta[f] - mu * sc;
    bnp[f] = sc;
    bnp[64 + f] = sh;
}

// ---------------------------------------------------------------------------
// Final: out[i] = sum_f (hpre[i][f]*sc[f]+sh[f]) * fcw[f] + fcb
// ---------------------------------------------------------------------------
__global__ __launch_bounds__(256) void final_kernel(const float* __restrict__ hpre,
                                                    const float* __restrict__ bnp,
                                                    const float* __restrict__ fcw,
                                                    const float* __restrict__ fcb,
                                                    float* __restrict__ out, int n) {
    int wave = threadIdx.x >> 6;
    int lane = threadIdx.x & 63;
    int node = blockIdx.x * 4 + wave;
    if (node < n) {
        float v = hpre[(size_t)node * HID + lane];
        float t = fmaf(v, bnp[lane], bnp[64 + lane]) * fcw[lane];
        for (int off = 32; off > 0; off >>= 1) t += __shfl_xor(t, off);
        if (lane == 0) out[node] = t + fcb[0];
    }
}

// ---------------------------------------------------------------------------
extern "C" void kernel_launch(void* const* d_in, const int* in_sizes, int n_in,
                              void* d_out, int out_size, void* d_ws, size_t ws_size,
                              hipStream_t stream) {
    const float* x      = (const float*)d_in[0];
    const int*   ei     = (const int*)d_in[1];
    const float* w1a    = (const float*)d_in[2];
    const float* b1a    = (const float*)d_in[3];
    const float* w2a    = (const float*)d_in[4];
    const float* b2a    = (const float*)d_in[5];
    const float* w1s    = (const float*)d_in[6];
    const float* b1s    = (const float*)d_in[7];
    const float* w2s    = (const float*)d_in[8];
    const float* b2s    = (const float*)d_in[9];
    const float* eps    = (const float*)d_in[10];
    const float* gammas = (const float*)d_in[11];
    const float* betas  = (const float*)d_in[12];
    const float* fcw    = (const float*)d_in[13];
    const float* fcb    = (const float*)d_in[14];
    float* out = (float*)d_out;

    int n = in_sizes[0];          // 50000
    int E = in_sizes[1] / 2;      // 1600000
    int npad = ((n + 63) / 64) * 64;
    int nblk = npad / 64;
    int nbs = (n + 255) / 256;    // scan blocks

    const int* src = ei;
    const int* dst = ei + E;

    char* p = (char*)d_ws;
    float* zbuf    = (float*)p; p += (size_t)npad * HID * 4;
    float* hpre    = (float*)p; p += (size_t)npad * HID * 4;
    float* zscalar = (float*)p; p += (size_t)npad * 4;
    float* stats   = (float*)p; p += 4 * 128 * 4;   // [layer][sum(64), sumsq(64)]
    float* bnp     = (float*)p; p += 4 * 128 * 4;   // [layer][scale(64), shift(64)]
    int* deg      = (int*)p; p += (size_t)n * 4;
    int* rowptr   = (int*)p; p += (size_t)n * 4;
    int* cursor   = (int*)p; p += (size_t)n * 4;
    int* partial  = (int*)p; p += (size_t)n * 4;
    int* blocksum = (int*)p; p += (size_t)nbs * 4;
    int* blockoff = (int*)p; p += (size_t)nbs * 4;
    int* csr_src  = (int*)p; p += (size_t)E * 4;

    hipMemsetAsync(deg, 0, (size_t)n * 4, stream);
    hipMemsetAsync(stats, 0, 4 * 128 * 4, stream);

    // CSR build
    hist_kernel<<<(E + 255) / 256, 256, 0, stream>>>(dst, deg, E);
    scan_a_kernel<<<nbs, 256, 0, stream>>>(deg, partial, blocksum, n);
    scan_b_kernel<<<1, 256, 0, stream>>>(blocksum, blockoff, nbs);
    scan_c_kernel<<<nbs, 256, 0, stream>>>(partial, blockoff, rowptr, cursor, n);
    int wsz = (n + NWIN - 1) / NWIN;
    for (int w = 0; w < NWIN; ++w) {
        int lo = w * wsz;
        int hi = lo + wsz; if (hi > n) hi = n;
        scatter_win_kernel<<<(E + 255) / 256, 256, 0, stream>>>(src, dst, cursor, csr_src,
                                                                E, lo, hi);
    }

    // ---- Layer 1 (1 -> 64 -> 64) ----
    gather1_kernel<<<(n + 3) / 4, 256, 0, stream>>>(x, rowptr, deg, csr_src, eps, zscalar, n);
    mlp_kernel<<<nblk, 256, 0, stream>>>(zscalar, w1a, b1a, w2a, b2a, hpre, stats, n, 0);
    bnfin_kernel<<<1, 64, 0, stream>>>(stats, gammas, betas, bnp, n);

    // ---- Layers 2-4 (BN of previous layer folded into gatherz) ----
    for (int l = 1; l <= 3; ++l) {
        gatherz_kernel<<<(n + 3) / 4, 256, 0, stream>>>(hpre, bnp + (l - 1) * 128,
                                                        rowptr, deg, csr_src, eps, l, zbuf, n);
        mlp_kernel<<<nblk, 256, 0, stream>>>(zbuf,
                                             w1s + (size_t)(l - 1) * HID * HID,
                                             b1s + (size_t)(l - 1) * HID,
                                             w2s + (size_t)(l - 1) * HID * HID,
                                             b2s + (size_t)(l - 1) * HID,
                                             hpre, stats + l * 128, n, 1);
        bnfin_kernel<<<1, 64, 0, stream>>>(stats + l * 128, gammas + l * HID,
                                           betas + l * HID, bnp + l * 128, n);
    }
    final_kernel<<<(n + 3) / 4, 256, 0, stream>>>(hpre, bnp + 3 * 128, fcw, fcb, out, n);
}

// Round 4
// 496.005 us; speedup vs baseline: 1.5560x; 1.2561x over previous
//
#include <hip/hip_runtime.h>

#define HID 64
#define BN_EPS 1e-5f
#define WINSH 8          // 256 nodes per dst-window
#define WINSZ 256
#define B1 256           // bucketing blocks (phase 1/3)

// ---------------------------------------------------------------------------
// Atomic-free CSR build: two-level counting sort.
// P1: per-(window,block) counts via LDS. P2: scan. P3: bucket edges (packed).
// P4: per-window fine CSR via LDS histogram+scan. No global atomics anywhere.
// ---------------------------------------------------------------------------
__global__ __launch_bounds__(256) void p1_count_kernel(const int* __restrict__ dst,
                                                       int* __restrict__ cnt,
                                                       int E, int nw, int chunk) {
    __shared__ int c[256];
    int tid = threadIdx.x, b = blockIdx.x;
    c[tid] = 0;
    __syncthreads();
    int lo = b * chunk;
    int hi = lo + chunk; if (hi > E) hi = E;
    for (int e = lo + tid; e < hi; e += 256) atomicAdd(&c[dst[e] >> WINSH], 1);
    __syncthreads();
    if (tid < nw) cnt[tid * B1 + b] = c[tid];
}

// Generic hierarchical scan (also reused for any length): A = per-block scan
__global__ __launch_bounds__(256) void scan_a_kernel(const int* __restrict__ in,
                                                     int* __restrict__ partial,
                                                     int* __restrict__ blocksum, int n) {
    __shared__ int sums[256];
    int tid = threadIdx.x;
    int i = blockIdx.x * 256 + tid;
    int v = (i < n) ? in[i] : 0;
    sums[tid] = v;
    __syncthreads();
    for (int off = 1; off < 256; off <<= 1) {
        int t = (tid >= off) ? sums[tid - off] : 0;
        __syncthreads();
        sums[tid] += t;
        __syncthreads();
    }
    if (i < n) partial[i] = sums[tid] - v;      // exclusive
    if (tid == 255) blocksum[blockIdx.x] = sums[255];
}

__global__ __launch_bounds__(256) void scan_b_kernel(const int* __restrict__ blocksum,
                                                     int* __restrict__ blockoff, int nb) {
    __shared__ int s[256];
    __shared__ int carry;
    int tid = threadIdx.x;
    if (tid == 0) carry = 0;
    __syncthreads();
    for (int base = 0; base < nb; base += 256) {
        int i = base + tid;
        int v = (i < nb) ? blocksum[i] : 0;
        s[tid] = v;
        __syncthreads();
        for (int off = 1; off < 256; off <<= 1) {
            int t = (tid >= off) ? s[tid - off] : 0;
            __syncthreads();
            s[tid] += t;
            __syncthreads();
        }
        if (i < nb) blockoff[i] = carry + s[tid] - v;   // exclusive
        __syncthreads();
        if (tid == 0) carry += s[255];
        __syncthreads();
    }
}

__global__ __launch_bounds__(256) void scan_c_kernel(const int* __restrict__ partial,
                                                     const int* __restrict__ blockoff,
                                                     int* __restrict__ outp, int n) {
    int i = blockIdx.x * 256 + threadIdx.x;
    if (i < n) outp[i] = partial[i] + blockoff[blockIdx.x];
}

// P3: stable bucket by window. Each (window,block) cell owns a disjoint
// contiguous range of ebuf -> contiguous stores, no global atomics.
// Packed entry: src | (fine_node_id << 24)  (src < 2^24, window = 256 nodes)
__global__ __launch_bounds__(256) void p3_bucket_kernel(const int* __restrict__ src,
                                                        const int* __restrict__ dst,
                                                        const int* __restrict__ coff,
                                                        int* __restrict__ ebuf,
                                                        int E, int nw, int chunk) {
    __shared__ int cur[256];
    int tid = threadIdx.x, b = blockIdx.x;
    if (tid < nw) cur[tid] = coff[tid * B1 + b];
    __syncthreads();
    int lo = b * chunk;
    int hi = lo + chunk; if (hi > E) hi = E;
    for (int e = lo + tid; e < hi; e += 256) {
        int d = dst[e];
        int w = d >> WINSH;
        int pos = atomicAdd(&cur[w], 1);           // LDS atomic
        ebuf[pos] = src[e] | ((d & (WINSZ - 1)) << 24);
    }
}

// P4: per-window fine CSR. Window edges are contiguous (~8k, L1/L2-hot).
__global__ __launch_bounds__(256) void p4_fine_kernel(const int* __restrict__ ebuf,
                                                      const int* __restrict__ coff,
                                                      int* __restrict__ csr_src,
                                                      int* __restrict__ rowptr,
                                                      int* __restrict__ deg,
                                                      int E, int n, int nw) {
    __shared__ int fcnt[256];
    __shared__ int foff[256];
    int tid = threadIdx.x, w = blockIdx.x;
    int lo = coff[w * B1];
    int hi = (w + 1 < nw) ? coff[(w + 1) * B1] : E;
    fcnt[tid] = 0;
    __syncthreads();
    for (int e = lo + tid; e < hi; e += 256) atomicAdd(&fcnt[(unsigned)ebuf[e] >> 24], 1);
    __syncthreads();
    int v = fcnt[tid];
    foff[tid] = v;
    __syncthreads();
    for (int off = 1; off < 256; off <<= 1) {
        int t = (tid >= off) ? foff[tid - off] : 0;
        __syncthreads();
        foff[tid] += t;
        __syncthreads();
    }
    int myoff = lo + foff[tid] - v;     // exclusive within window, global offset
    int node = w * WINSZ + tid;
    if (node < n) { rowptr[node] = myoff; deg[node] = v; }
    __syncthreads();
    fcnt[tid] = myoff;                  // reuse as cursor
    __syncthreads();
    for (int e = lo + tid; e < hi; e += 256) {
        int p = ebuf[e];
        int pos = atomicAdd(&fcnt[(unsigned)p >> 24], 1);   // LDS atomic
        csr_src[pos] = p & 0xFFFFFF;
    }
}

// ---------------------------------------------------------------------------
// Layer 1 scalar aggregation: z[i] = (1+eps0)*x[i] + sum_{src in N(i)} x[src]
// ---------------------------------------------------------------------------
__global__ __launch_bounds__(256) void gather1_kernel(const float* __restrict__ x,
                                                      const int* __restrict__ rowptr,
                                                      const int* __restrict__ deg,
                                                      const int* __restrict__ csr_src,
                                                      const float* __restrict__ eps,
                                                      float* __restrict__ zscalar, int n) {
    int node = blockIdx.x * 4 + (threadIdx.x >> 6);
    int lane = threadIdx.x & 63;
    if (node >= n) return;
    int start = __builtin_amdgcn_readfirstlane(rowptr[node]);
    int cnt   = __builtin_amdgcn_readfirstlane(deg[node]);
    float a = 0.f;
    for (int i = lane; i < cnt; i += 64) a += x[csr_src[start + i]];
    for (int off = 32; off > 0; off >>= 1) a += __shfl_xor(a, off);
    if (lane == 0) zscalar[node] = (1.0f + eps[0]) * x[node] + a;
}

// ---------------------------------------------------------------------------
// Layers 2-4 aggregation with BN of the PREVIOUS layer folded in:
//   z = sc*(ep*hp_i + sum_s hp_s) + sh*(ep + deg)
// ---------------------------------------------------------------------------
__global__ __launch_bounds__(256) void gatherz_kernel(const float* __restrict__ hpre,
                                                      const float* __restrict__ bnp,
                                                      const int* __restrict__ rowptr,
                                                      const int* __restrict__ deg,
                                                      const int* __restrict__ csr_src,
                                                      const float* __restrict__ eps,
                                                      int layer,
                                                      float* __restrict__ zbuf, int n) {
    int node = blockIdx.x * 4 + (threadIdx.x >> 6);
    int lane = threadIdx.x & 63;
    if (node >= n) return;
    int start = __builtin_amdgcn_readfirstlane(rowptr[node]);
    int cnt   = __builtin_amdgcn_readfirstlane(deg[node]);
    float a0 = 0.f, a1 = 0.f, a2 = 0.f, a3 = 0.f;
    float a4 = 0.f, a5 = 0.f, a6 = 0.f, a7 = 0.f;
    int e = 0;
    for (; e + 8 <= cnt; e += 8) {
        int s0 = csr_src[start + e + 0];
        int s1 = csr_src[start + e + 1];
        int s2 = csr_src[start + e + 2];
        int s3 = csr_src[start + e + 3];
        int s4 = csr_src[start + e + 4];
        int s5 = csr_src[start + e + 5];
        int s6 = csr_src[start + e + 6];
        int s7 = csr_src[start + e + 7];
        a0 += hpre[(size_t)s0 * HID + lane];
        a1 += hpre[(size_t)s1 * HID + lane];
        a2 += hpre[(size_t)s2 * HID + lane];
        a3 += hpre[(size_t)s3 * HID + lane];
        a4 += hpre[(size_t)s4 * HID + lane];
        a5 += hpre[(size_t)s5 * HID + lane];
        a6 += hpre[(size_t)s6 * HID + lane];
        a7 += hpre[(size_t)s7 * HID + lane];
    }
    for (; e < cnt; ++e) a0 += hpre[(size_t)csr_src[start + e] * HID + lane];
    float sum = ((a0 + a1) + (a2 + a3)) + ((a4 + a5) + (a6 + a7));
    float ep = 1.0f + eps[layer];
    float sc = bnp[lane], sh = bnp[64 + lane];
    float self = hpre[(size_t)node * HID + lane];
    zbuf[(size_t)node * HID + lane] =
        fmaf(sc, fmaf(ep, self, sum), sh * (ep + (float)cnt));
}

// ---------------------------------------------------------------------------
// MLP tile kernel: 64 nodes per block, 256 threads, 4x4 micro-tiles.
// ---------------------------------------------------------------------------
__global__ __launch_bounds__(256) void mlp_kernel(const float* __restrict__ zin,
                                                  const float* __restrict__ W1,
                                                  const float* __restrict__ b1,
                                                  const float* __restrict__ W2,
                                                  const float* __restrict__ b2,
                                                  float* __restrict__ hpre,
                                                  float* __restrict__ stats,
                                                  int n, int mode) {
    __shared__ float Ws1[HID * HID];
    __shared__ float Ws2[HID * HID];
    __shared__ float Tile[HID * (HID + 1)];  // +1 pad vs bank conflicts

    int tid = threadIdx.x;
    int base = blockIdx.x * 64;

    for (int i = tid; i < HID * HID; i += 256) {
        Ws2[i] = W2[i];
        if (mode) Ws1[i] = W1[i];
    }

    if (mode) {
        for (int idx = tid; idx < 64 * HID; idx += 256) {
            int nn = idx >> 6, k = idx & 63;
            Tile[nn * 65 + k] = zin[(base + nn) * HID + k];
        }
    } else {
        for (int idx = tid; idx < 64 * HID; idx += 256) {
            int nn = idx >> 6, k = idx & 63;
            float zv = zin[base + nn];
            Tile[nn * 65 + k] = fmaxf(fmaf(zv, W1[k], b1[k]), 0.f);
        }
    }
    __syncthreads();

    int r0 = (tid >> 4) * 4;
    int c0 = (tid & 15) * 4;

    float acc[4][4];
#pragma unroll
    for (int i = 0; i < 4; ++i)
#pragma unroll
        for (int j = 0; j < 4; ++j) acc[i][j] = 0.f;

    if (mode) {
        for (int k = 0; k < HID; ++k) {
            float4 w = *(const float4*)&Ws1[k * HID + c0];
#pragma unroll
            for (int i = 0; i < 4; ++i) {
                float a = Tile[(r0 + i) * 65 + k];
                acc[i][0] = fmaf(a, w.x, acc[i][0]);
                acc[i][1] = fmaf(a, w.y, acc[i][1]);
                acc[i][2] = fmaf(a, w.z, acc[i][2]);
                acc[i][3] = fmaf(a, w.w, acc[i][3]);
            }
        }
        __syncthreads();
#pragma unroll
        for (int i = 0; i < 4; ++i)
#pragma unroll
            for (int j = 0; j < 4; ++j)
                Tile[(r0 + i) * 65 + c0 + j] = fmaxf(acc[i][j] + b1[c0 + j], 0.f);
#pragma unroll
        for (int i = 0; i < 4; ++i)
#pragma unroll
            for (int j = 0; j < 4; ++j) acc[i][j] = 0.f;
        __syncthreads();
    }

    // GEMM2: Hpre = relu(T @ W2 + b2)
    for (int k = 0; k < HID; ++k) {
        float4 w = *(const float4*)&Ws2[k * HID + c0];
#pragma unroll
        for (int i = 0; i < 4; ++i) {
            float a = Tile[(r0 + i) * 65 + k];
            acc[i][0] = fmaf(a, w.x, acc[i][0]);
            acc[i][1] = fmaf(a, w.y, acc[i][1]);
            acc[i][2] = fmaf(a, w.z, acc[i][2]);
            acc[i][3] = fmaf(a, w.w, acc[i][3]);
        }
    }

    float hv[4][4];
#pragma unroll
    for (int i = 0; i < 4; ++i)
#pragma unroll
        for (int j = 0; j < 4; ++j) hv[i][j] = fmaxf(acc[i][j] + b2[c0 + j], 0.f);

    __syncthreads();  // GEMM2 done reading Tile
#pragma unroll
    for (int i = 0; i < 4; ++i)
#pragma unroll
        for (int j = 0; j < 4; ++j) Tile[(r0 + i) * 65 + c0 + j] = hv[i][j];
    __syncthreads();

    // store valid rows
#pragma unroll
    for (int i = 0; i < 4; ++i) {
        int node = base + r0 + i;
        if (node < n) {
            float4 o = make_float4(hv[i][0], hv[i][1], hv[i][2], hv[i][3]);
            *(float4*)&hpre[node * HID + c0] = o;
        }
    }

    // per-feature stats over valid rows of this tile
    if (tid < 64) {
        int lim = n - base; if (lim > 64) lim = 64;
        float s = 0.f, s2 = 0.f;
        for (int r = 0; r < lim; ++r) {
            float v = Tile[r * 65 + tid];
            s += v;
            s2 = fmaf(v, v, s2);
        }
        atomicAdd(&stats[tid], s);
        atomicAdd(&stats[64 + tid], s2);
    }
}

// ---------------------------------------------------------------------------
// BN finalize: scale/shift per feature
// ---------------------------------------------------------------------------
__global__ __launch_bounds__(64) void bnfin_kernel(const float* __restrict__ stats,
                                                   const float* __restrict__ gamma,
                                                   const float* __restrict__ beta,
                                                   float* __restrict__ bnp, int n) {
    int f = threadIdx.x;
    float inv_n = 1.0f / (float)n;
    float mu = stats[f] * inv_n;
    float var = stats[64 + f] * inv_n - mu * mu;
    float inv = rsqrtf(var + BN_EPS);
    float sc = gamma[f] * inv;
    float sh = beta[f] - mu * sc;
    bnp[f] = sc;
    bnp[64 + f] = sh;
}

// ---------------------------------------------------------------------------
// Final: out[i] = sum_f (hpre[i][f]*sc[f]+sh[f]) * fcw[f] + fcb
// ---------------------------------------------------------------------------
__global__ __launch_bounds__(256) void final_kernel(const float* __restrict__ hpre,
                                                    const float* __restrict__ bnp,
                                                    const float* __restrict__ fcw,
                                                    const float* __restrict__ fcb,
                                                    float* __restrict__ out, int n) {
    int wave = threadIdx.x >> 6;
    int lane = threadIdx.x & 63;
    int node = blockIdx.x * 4 + wave;
    if (node < n) {
        float v = hpre[(size_t)node * HID + lane];
        float t = fmaf(v, bnp[lane], bnp[64 + lane]) * fcw[lane];
        for (int off = 32; off > 0; off >>= 1) t += __shfl_xor(t, off);
        if (lane == 0) out[node] = t + fcb[0];
    }
}

// ---------------------------------------------------------------------------
extern "C" void kernel_launch(void* const* d_in, const int* in_sizes, int n_in,
                              void* d_out, int out_size, void* d_ws, size_t ws_size,
                              hipStream_t stream) {
    const float* x      = (const float*)d_in[0];
    const int*   ei     = (const int*)d_in[1];
    const float* w1a    = (const float*)d_in[2];
    const float* b1a    = (const float*)d_in[3];
    const float* w2a    = (const float*)d_in[4];
    const float* b2a    = (const float*)d_in[5];
    const float* w1s    = (const float*)d_in[6];
    const float* b1s    = (const float*)d_in[7];
    const float* w2s    = (const float*)d_in[8];
    const float* b2s    = (const float*)d_in[9];
    const float* eps    = (const float*)d_in[10];
    const float* gammas = (const float*)d_in[11];
    const float* betas  = (const float*)d_in[12];
    const float* fcw    = (const float*)d_in[13];
    const float* fcb    = (const float*)d_in[14];
    float* out = (float*)d_out;

    int n = in_sizes[0];          // 50000
    int E = in_sizes[1] / 2;      // 1600000
    int npad = ((n + 63) / 64) * 64;
    int nblk = npad / 64;

    int nw = (n + WINSZ - 1) >> WINSH;      // 196 windows
    int NWB = nw * B1;                      // count-matrix cells
    int chunk = (E + B1 - 1) / B1;          // edges per bucketing block
    int nbs2 = (NWB + 255) / 256;           // scan blocks over count matrix

    const int* src = ei;
    const int* dst = ei + E;

    char* p = (char*)d_ws;
    float* zbuf    = (float*)p; p += (size_t)npad * HID * 4;
    float* hpre    = (float*)p; p += (size_t)npad * HID * 4;
    float* zscalar = (float*)p; p += (size_t)npad * 4;
    float* stats   = (float*)p; p += 4 * 128 * 4;   // [layer][sum(64), sumsq(64)]
    float* bnp     = (float*)p; p += 4 * 128 * 4;   // [layer][scale(64), shift(64)]
    int* deg     = (int*)p; p += (size_t)n * 4;
    int* rowptr  = (int*)p; p += (size_t)n * 4;
    int* csr_src = (int*)p; p += (size_t)E * 4;

    // CSR-build temporaries alias into zbuf (dead until first gatherz):
    // ebuf E + cnt NWB + cpart NWB + coff NWB + bsum/boff ~ 7 MB < 12.8 MB
    int* ebuf  = (int*)zbuf;
    int* cnt   = ebuf + E;
    int* cpart = cnt + NWB;
    int* coff  = cpart + NWB;
    int* bsum  = coff + NWB;
    int* boff  = bsum + nbs2;

    hipMemsetAsync(stats, 0, 4 * 128 * 4, stream);

    // ---- CSR build (no global atomics) ----
    p1_count_kernel<<<B1, 256, 0, stream>>>(dst, cnt, E, nw, chunk);
    scan_a_kernel<<<nbs2, 256, 0, stream>>>(cnt, cpart, bsum, NWB);
    scan_b_kernel<<<1, 256, 0, stream>>>(bsum, boff, nbs2);
    scan_c_kernel<<<nbs2, 256, 0, stream>>>(cpart, boff, coff, NWB);
    p3_bucket_kernel<<<B1, 256, 0, stream>>>(src, dst, coff, ebuf, E, nw, chunk);
    p4_fine_kernel<<<nw, 256, 0, stream>>>(ebuf, coff, csr_src, rowptr, deg, E, n, nw);

    // ---- Layer 1 (1 -> 64 -> 64) ----
    gather1_kernel<<<(n + 3) / 4, 256, 0, stream>>>(x, rowptr, deg, csr_src, eps, zscalar, n);
    mlp_kernel<<<nblk, 256, 0, stream>>>(zscalar, w1a, b1a, w2a, b2a, hpre, stats, n, 0);
    bnfin_kernel<<<1, 64, 0, stream>>>(stats, gammas, betas, bnp, n);

    // ---- Layers 2-4 (BN of previous layer folded into gatherz) ----
    for (int l = 1; l <= 3; ++l) {
        gatherz_kernel<<<(n + 3) / 4, 256, 0, stream>>>(hpre, bnp + (l - 1) * 128,
                                                        rowptr, deg, csr_src, eps, l, zbuf, n);
        mlp_kernel<<<nblk, 256, 0, stream>>>(zbuf,
                                             w1s + (size_t)(l - 1) * HID * HID,
                                             b1s + (size_t)(l - 1) * HID,
                                             w2s + (size_t)(l - 1) * HID * HID,
                                             b2s + (size_t)(l - 1) * HID,
                                             hpre, stats + l * 128, n, 1);
        bnfin_kernel<<<1, 64, 0, stream>>>(stats + l * 128, gammas + l * HID,
                                           betas + l * HID, bnp + l * 128, n);
    }
    final_kernel<<<(n + 3) / 4, 256, 0, stream>>>(hpre, bnp + 3 * 128, fcw, fcb, out, n);
}

// Round 6
// 442.093 us; speedup vs baseline: 1.7458x; 1.1219x over previous
//
#include <hip/hip_runtime.h>

#define HID 64
#define BN_EPS 1e-5f
#define WINSH 8          // 256 nodes per dst-window
#define WINSZ 256
#define B1 256           // bucketing blocks (phase 1/3)
#define PIT 72           // LDS pitch in shorts (16B-aligned fragment reads)

typedef short bf16x8 __attribute__((ext_vector_type(8)));
typedef float f32x4 __attribute__((ext_vector_type(4)));

__device__ __forceinline__ unsigned short f2b(float f) {
    unsigned int u = __float_as_uint(f);
    u = (u + 0x7FFF + ((u >> 16) & 1)) >> 16;   // RNE
    return (unsigned short)u;
}
__device__ __forceinline__ float b2f(unsigned short h) {
    return __uint_as_float(((unsigned int)h) << 16);
}
__device__ __forceinline__ f32x4 mfma_bf16(bf16x8 a, bf16x8 b, f32x4 c) {
    return __builtin_amdgcn_mfma_f32_16x16x32_bf16(a, b, c, 0, 0, 0);
}

// ---------------------------------------------------------------------------
// Atomic-free CSR build: two-level counting sort (unchanged from R4).
// ---------------------------------------------------------------------------
__global__ __launch_bounds__(256) void p1_count_kernel(const int* __restrict__ dst,
                                                       int* __restrict__ cnt,
                                                       int E, int nw, int chunk) {
    __shared__ int c[256];
    int tid = threadIdx.x, b = blockIdx.x;
    c[tid] = 0;
    __syncthreads();
    int lo = b * chunk;
    int hi = lo + chunk; if (hi > E) hi = E;
    for (int e = lo + tid; e < hi; e += 256) atomicAdd(&c[dst[e] >> WINSH], 1);
    __syncthreads();
    if (tid < nw) cnt[tid * B1 + b] = c[tid];
}

__global__ __launch_bounds__(256) void scan_a_kernel(const int* __restrict__ in,
                                                     int* __restrict__ partial,
                                                     int* __restrict__ blocksum, int n) {
    __shared__ int sums[256];
    int tid = threadIdx.x;
    int i = blockIdx.x * 256 + tid;
    int v = (i < n) ? in[i] : 0;
    sums[tid] = v;
    __syncthreads();
    for (int off = 1; off < 256; off <<= 1) {
        int t = (tid >= off) ? sums[tid - off] : 0;
        __syncthreads();
        sums[tid] += t;
        __syncthreads();
    }
    if (i < n) partial[i] = sums[tid] - v;
    if (tid == 255) blocksum[blockIdx.x] = sums[255];
}

__global__ __launch_bounds__(256) void scan_b_kernel(const int* __restrict__ blocksum,
                                                     int* __restrict__ blockoff, int nb) {
    __shared__ int s[256];
    __shared__ int carry;
    int tid = threadIdx.x;
    if (tid == 0) carry = 0;
    __syncthreads();
    for (int base = 0; base < nb; base += 256) {
        int i = base + tid;
        int v = (i < nb) ? blocksum[i] : 0;
        s[tid] = v;
        __syncthreads();
        for (int off = 1; off < 256; off <<= 1) {
            int t = (tid >= off) ? s[tid - off] : 0;
            __syncthreads();
            s[tid] += t;
            __syncthreads();
        }
        if (i < nb) blockoff[i] = carry + s[tid] - v;
        __syncthreads();
        if (tid == 0) carry += s[255];
        __syncthreads();
    }
}

__global__ __launch_bounds__(256) void scan_c_kernel(const int* __restrict__ partial,
                                                     const int* __restrict__ blockoff,
                                                     int* __restrict__ outp, int n) {
    int i = blockIdx.x * 256 + threadIdx.x;
    if (i < n) outp[i] = partial[i] + blockoff[blockIdx.x];
}

__global__ __launch_bounds__(256) void p3_bucket_kernel(const int* __restrict__ src,
                                                        const int* __restrict__ dst,
                                                        const int* __restrict__ coff,
                                                        int* __restrict__ ebuf,
                                                        int E, int nw, int chunk) {
    __shared__ int cur[256];
    int tid = threadIdx.x, b = blockIdx.x;
    if (tid < nw) cur[tid] = coff[tid * B1 + b];
    __syncthreads();
    int lo = b * chunk;
    int hi = lo + chunk; if (hi > E) hi = E;
    for (int e = lo + tid; e < hi; e += 256) {
        int d = dst[e];
        int w = d >> WINSH;
        int pos = atomicAdd(&cur[w], 1);           // LDS atomic
        ebuf[pos] = src[e] | ((d & (WINSZ - 1)) << 24);
    }
}

__global__ __launch_bounds__(256) void p4_fine_kernel(const int* __restrict__ ebuf,
                                                      const int* __restrict__ coff,
                                                      int* __restrict__ csr_src,
                                                      int* __restrict__ rowptr,
                                                      int* __restrict__ deg,
                                                      int E, int n, int nw) {
    __shared__ int fcnt[256];
    __shared__ int foff[256];
    int tid = threadIdx.x, w = blockIdx.x;
    int lo = coff[w * B1];
    int hi = (w + 1 < nw) ? coff[(w + 1) * B1] : E;
    fcnt[tid] = 0;
    __syncthreads();
    for (int e = lo + tid; e < hi; e += 256) atomicAdd(&fcnt[(unsigned)ebuf[e] >> 24], 1);
    __syncthreads();
    int v = fcnt[tid];
    foff[tid] = v;
    __syncthreads();
    for (int off = 1; off < 256; off <<= 1) {
        int t = (tid >= off) ? foff[tid - off] : 0;
        __syncthreads();
        foff[tid] += t;
        __syncthreads();
    }
    int myoff = lo + foff[tid] - v;
    int node = w * WINSZ + tid;
    if (node < n) { rowptr[node] = myoff; deg[node] = v; }
    __syncthreads();
    fcnt[tid] = myoff;
    __syncthreads();
    for (int e = lo + tid; e < hi; e += 256) {
        int p = ebuf[e];
        int pos = atomicAdd(&fcnt[(unsigned)p >> 24], 1);   // LDS atomic
        csr_src[pos] = p & 0xFFFFFF;
    }
}

// ---------------------------------------------------------------------------
// Weight prep: split each 64x64 W into hi/lo bf16 pair, stored in MFMA
// B-FRAGMENT ORDER so mlp lanes load one 16B dwordx4 per fragment.
// frag index: (((nt*2+kh)*64 + lane)*8 + j), element = W[k][n'] with
//   n' = nt*16 + (lane&15),  k = kh*32 + (lane>>4)*8 + j.
// slots: 0 = w2a, 1..3 = w1s[i], 4..6 = w2s[i]
// ---------------------------------------------------------------------------
__global__ __launch_bounds__(256) void wprep_kernel(const float* __restrict__ w2a,
                                                    const float* __restrict__ w1s,
                                                    const float* __restrict__ w2s,
                                                    unsigned short* __restrict__ whi,
                                                    unsigned short* __restrict__ wlo) {
    int b = blockIdx.x;
    const float* srcm = (b == 0) ? w2a : (b <= 3 ? w1s + (size_t)(b - 1) * 4096
                                                 : w2s + (size_t)(b - 4) * 4096);
    unsigned short* dh = whi + (size_t)b * 4096;
    unsigned short* dl = wlo + (size_t)b * 4096;
    for (int idx = threadIdx.x; idx < 4096; idx += 256) {
        int j = idx & 7;
        int lane = (idx >> 3) & 63;
        int ntkh = idx >> 9;               // 0..7
        int nt = ntkh >> 1, kh = ntkh & 1;
        int nc = nt * 16 + (lane & 15);
        int k = kh * 32 + (lane >> 4) * 8 + j;
        float v = srcm[k * 64 + nc];
        unsigned short h = f2b(v);
        dh[idx] = h;
        dl[idx] = f2b(v - b2f(h));
    }
}

// ---------------------------------------------------------------------------
// Layer 1 scalar aggregation (unchanged)
// ---------------------------------------------------------------------------
__global__ __launch_bounds__(256) void gather1_kernel(const float* __restrict__ x,
                                                      const int* __restrict__ rowptr,
                                                      const int* __restrict__ deg,
                                                      const int* __restrict__ csr_src,
                                                      const float* __restrict__ eps,
                                                      float* __restrict__ zscalar, int n) {
    int node = blockIdx.x * 4 + (threadIdx.x >> 6);
    int lane = threadIdx.x & 63;
    if (node >= n) return;
    int start = __builtin_amdgcn_readfirstlane(rowptr[node]);
    int cnt   = __builtin_amdgcn_readfirstlane(deg[node]);
    float a = 0.f;
    for (int i = lane; i < cnt; i += 64) a += x[csr_src[start + i]];
    for (int off = 32; off > 0; off >>= 1) a += __shfl_xor(a, off);
    if (lane == 0) zscalar[node] = (1.0f + eps[0]) * x[node] + a;
}

// ---------------------------------------------------------------------------
// Layers 2-4 aggregation, BN folded; fp32 output (no rounding here).
// ---------------------------------------------------------------------------
__global__ __launch_bounds__(256) void gatherz_kernel(const float* __restrict__ hpre,
                                                      const float* __restrict__ bnp,
                                                      const int* __restrict__ rowptr,
                                                      const int* __restrict__ deg,
                                                      const int* __restrict__ csr_src,
                                                      const float* __restrict__ eps,
                                                      int layer,
                                                      float* __restrict__ zbuf, int n) {
    int node = blockIdx.x * 4 + (threadIdx.x >> 6);
    int lane = threadIdx.x & 63;
    if (node >= n) return;
    int start = __builtin_amdgcn_readfirstlane(rowptr[node]);
    int cnt   = __builtin_amdgcn_readfirstlane(deg[node]);
    float a0 = 0.f, a1 = 0.f, a2 = 0.f, a3 = 0.f;
    float a4 = 0.f, a5 = 0.f, a6 = 0.f, a7 = 0.f;
    int e = 0;
    for (; e + 8 <= cnt; e += 8) {
        int s0 = csr_src[start + e + 0];
        int s1 = csr_src[start + e + 1];
        int s2 = csr_src[start + e + 2];
        int s3 = csr_src[start + e + 3];
        int s4 = csr_src[start + e + 4];
        int s5 = csr_src[start + e + 5];
        int s6 = csr_src[start + e + 6];
        int s7 = csr_src[start + e + 7];
        a0 += hpre[(size_t)s0 * HID + lane];
        a1 += hpre[(size_t)s1 * HID + lane];
        a2 += hpre[(size_t)s2 * HID + lane];
        a3 += hpre[(size_t)s3 * HID + lane];
        a4 += hpre[(size_t)s4 * HID + lane];
        a5 += hpre[(size_t)s5 * HID + lane];
        a6 += hpre[(size_t)s6 * HID + lane];
        a7 += hpre[(size_t)s7 * HID + lane];
    }
    for (; e < cnt; ++e) a0 += hpre[(size_t)csr_src[start + e] * HID + lane];
    float sum = ((a0 + a1) + (a2 + a3)) + ((a4 + a5) + (a6 + a7));
    float ep = 1.0f + eps[layer];
    float sc = bnp[lane], sh = bnp[64 + lane];
    float self = hpre[(size_t)node * HID + lane];
    zbuf[(size_t)node * HID + lane] =
        fmaf(sc, fmaf(ep, self, sum), sh * (ep + (float)cnt));
}

// ---------------------------------------------------------------------------
// MFMA MLP with split-bf16 (hi/lo) precision: A*B ~= AhBh + AhBl + AlBh.
// 64-node tile, 4 waves; wave w owns rows w*16..w*16+15.
// A planes (Z then T) in LDS; W fragments loaded from pre-swizzled global.
// Layouts (m89/m118/m120-verified): A[m=lane&15][k=quad*8+j],
// B[n=lane&15][k=quad*8+j], D: col=lane&15, row=quad*4+reg.
// ---------------------------------------------------------------------------
__global__ __launch_bounds__(256) void mlp_kernel(const float* __restrict__ zin,
                                                  const float* __restrict__ zscalar,
                                                  const float* __restrict__ w1a,
                                                  const float* __restrict__ b1a,
                                                  const unsigned short* __restrict__ w1h,
                                                  const unsigned short* __restrict__ w1l,
                                                  const float* __restrict__ b1v,
                                                  const unsigned short* __restrict__ w2h,
                                                  const unsigned short* __restrict__ w2l,
                                                  const float* __restrict__ b2v,
                                                  float* __restrict__ hpre,
                                                  float* __restrict__ stats,
                                                  int n, int mode) {
    __shared__ __align__(16) unsigned short Ah[64 * PIT];
    __shared__ __align__(16) unsigned short Al[64 * PIT];
    __shared__ float ssum[64], ssq[64];

    int tid = threadIdx.x;
    int base = blockIdx.x * 64;

    if (mode) {
        for (int i = tid; i < 4096; i += 256) {
            int nn = i >> 6, k = i & 63;
            float v = zin[(size_t)(base + nn) * HID + k];
            unsigned short h = f2b(v);
            Ah[nn * PIT + k] = h;
            Al[nn * PIT + k] = f2b(v - b2f(h));
        }
    } else {
        for (int i = tid; i < 4096; i += 256) {
            int nn = i >> 6, k = i & 63;
            float zv = zscalar[base + nn];
            float v = fmaxf(fmaf(zv, w1a[k], b1a[k]), 0.f);
            unsigned short h = f2b(v);
            Ah[nn * PIT + k] = h;
            Al[nn * PIT + k] = f2b(v - b2f(h));
        }
    }
    if (tid < 64) { ssum[tid] = 0.f; ssq[tid] = 0.f; }
    __syncthreads();

    int l = tid & 63;
    int m = l & 15;            // A/B free index; D col
    int q = l >> 4;            // quad; D row block
    int m0 = (tid >> 6) * 16;  // wave's node-row block

    const bf16x8* a0h = (const bf16x8*)&Ah[(m0 + m) * PIT + q * 8];
    const bf16x8* a1h = (const bf16x8*)&Ah[(m0 + m) * PIT + 32 + q * 8];
    const bf16x8* a0l = (const bf16x8*)&Al[(m0 + m) * PIT + q * 8];
    const bf16x8* a1l = (const bf16x8*)&Al[(m0 + m) * PIT + 32 + q * 8];

    if (mode) {
        // GEMM1: T = relu(Z @ W1 + b1), split arithmetic
        bf16x8 xa0h = *a0h, xa1h = *a1h, xa0l = *a0l, xa1l = *a1l;
        f32x4 acc[4];
#pragma unroll
        for (int nt = 0; nt < 4; ++nt) {
            size_t fo0 = ((size_t)(nt * 2 + 0) * 64 + l) * 8;
            size_t fo1 = ((size_t)(nt * 2 + 1) * 64 + l) * 8;
            bf16x8 b0h = *(const bf16x8*)(w1h + fo0);
            bf16x8 b1h_ = *(const bf16x8*)(w1h + fo1);
            bf16x8 b0l = *(const bf16x8*)(w1l + fo0);
            bf16x8 b1l_ = *(const bf16x8*)(w1l + fo1);
            f32x4 c = {0.f, 0.f, 0.f, 0.f};
            c = mfma_bf16(xa0h, b0h, c);
            c = mfma_bf16(xa0h, b0l, c);
            c = mfma_bf16(xa0l, b0h, c);
            c = mfma_bf16(xa1h, b1h_, c);
            c = mfma_bf16(xa1h, b1l_, c);
            c = mfma_bf16(xa1l, b1h_, c);
            acc[nt] = c;
        }
        // write T back to A planes (each wave owns its 16 rows; reads above
        // completed into registers before these stores)
#pragma unroll
        for (int nt = 0; nt < 4; ++nt) {
            int col = nt * 16 + m;
            float bv = b1v[col];
#pragma unroll
            for (int r = 0; r < 4; ++r) {
                int row = m0 + q * 4 + r;
                float T = fmaxf(acc[nt][r] + bv, 0.f);
                unsigned short h = f2b(T);
                Ah[row * PIT + col] = h;
                Al[row * PIT + col] = f2b(T - b2f(h));
            }
        }
    }
    __syncthreads();

    // GEMM2: H = relu(T @ W2 + b2), split arithmetic
    {
        bf16x8 xa0h = *a0h, xa1h = *a1h, xa0l = *a0l, xa1l = *a1l;
        f32x4 acc[4];
#pragma unroll
        for (int nt = 0; nt < 4; ++nt) {
            size_t fo0 = ((size_t)(nt * 2 + 0) * 64 + l) * 8;
            size_t fo1 = ((size_t)(nt * 2 + 1) * 64 + l) * 8;
            bf16x8 b0h = *(const bf16x8*)(w2h + fo0);
            bf16x8 b1h_ = *(const bf16x8*)(w2h + fo1);
            bf16x8 b0l = *(const bf16x8*)(w2l + fo0);
            bf16x8 b1l_ = *(const bf16x8*)(w2l + fo1);
            f32x4 c = {0.f, 0.f, 0.f, 0.f};
            c = mfma_bf16(xa0h, b0h, c);
            c = mfma_bf16(xa0h, b0l, c);
            c = mfma_bf16(xa0l, b0h, c);
            c = mfma_bf16(xa1h, b1h_, c);
            c = mfma_bf16(xa1h, b1l_, c);
            c = mfma_bf16(xa1l, b1h_, c);
            acc[nt] = c;
        }
#pragma unroll
        for (int nt = 0; nt < 4; ++nt) {
            int col = nt * 16 + m;
            float bv = b2v[col];
            float cs = 0.f, cq = 0.f;
#pragma unroll
            for (int r = 0; r < 4; ++r) {
                int node = base + m0 + q * 4 + r;
                float h = fmaxf(acc[nt][r] + bv, 0.f);
                if (node < n) {
                    hpre[(size_t)node * HID + col] = h;
                    cs += h;
                    cq = fmaf(h, h, cq);
                }
            }
            cs += __shfl_xor(cs, 16); cs += __shfl_xor(cs, 32);
            cq += __shfl_xor(cq, 16); cq += __shfl_xor(cq, 32);
            if (q == 0) {
                atomicAdd(&ssum[col], cs);
                atomicAdd(&ssq[col], cq);
            }
        }
    }
    __syncthreads();
    if (tid < 64) {
        atomicAdd(&stats[tid], ssum[tid]);
        atomicAdd(&stats[64 + tid], ssq[tid]);
    }
}

// ---------------------------------------------------------------------------
// BN finalize (unchanged)
// ---------------------------------------------------------------------------
__global__ __launch_bounds__(64) void bnfin_kernel(const float* __restrict__ stats,
                                                   const float* __restrict__ gamma,
                                                   const float* __restrict__ beta,
                                                   float* __restrict__ bnp, int n) {
    int f = threadIdx.x;
    float inv_n = 1.0f / (float)n;
    float mu = stats[f] * inv_n;
    float var = stats[64 + f] * inv_n - mu * mu;
    float inv = rsqrtf(var + BN_EPS);
    float sc = gamma[f] * inv;
    float sh = beta[f] - mu * sc;
    bnp[f] = sc;
    bnp[64 + f] = sh;
}

// ---------------------------------------------------------------------------
// Final (unchanged)
// ---------------------------------------------------------------------------
__global__ __launch_bounds__(256) void final_kernel(const float* __restrict__ hpre,
                                                    const float* __restrict__ bnp,
                                                    const float* __restrict__ fcw,
                                                    const float* __restrict__ fcb,
                                                    float* __restrict__ out, int n) {
    int wave = threadIdx.x >> 6;
    int lane = threadIdx.x & 63;
    int node = blockIdx.x * 4 + wave;
    if (node < n) {
        float v = hpre[(size_t)node * HID + lane];
        float t = fmaf(v, bnp[lane], bnp[64 + lane]) * fcw[lane];
        for (int off = 32; off > 0; off >>= 1) t += __shfl_xor(t, off);
        if (lane == 0) out[node] = t + fcb[0];
    }
}

// ---------------------------------------------------------------------------
extern "C" void kernel_launch(void* const* d_in, const int* in_sizes, int n_in,
                              void* d_out, int out_size, void* d_ws, size_t ws_size,
                              hipStream_t stream) {
    const float* x      = (const float*)d_in[0];
    const int*   ei     = (const int*)d_in[1];
    const float* w1a    = (const float*)d_in[2];
    const float* b1a    = (const float*)d_in[3];
    const float* w2a    = (const float*)d_in[4];
    const float* b2a    = (const float*)d_in[5];
    const float* w1s    = (const float*)d_in[6];
    const float* b1s    = (const float*)d_in[7];
    const float* w2s    = (const float*)d_in[8];
    const float* b2s    = (const float*)d_in[9];
    const float* eps    = (const float*)d_in[10];
    const float* gammas = (const float*)d_in[11];
    const float* betas  = (const float*)d_in[12];
    const float* fcw    = (const float*)d_in[13];
    const float* fcb    = (const float*)d_in[14];
    float* out = (float*)d_out;

    int n = in_sizes[0];          // 50000
    int E = in_sizes[1] / 2;      // 1600000
    int npad = ((n + 63) / 64) * 64;
    int nblk = npad / 64;

    int nw = (n + WINSZ - 1) >> WINSH;      // 196 windows
    int NWB = nw * B1;
    int chunk = (E + B1 - 1) / B1;
    int nbs2 = (NWB + 255) / 256;

    const int* src = ei;
    const int* dst = ei + E;

    char* p = (char*)d_ws;
    float* zbuf    = (float*)p; p += (size_t)npad * HID * 4;   // aliased by CSR temps
    float* hpre    = (float*)p; p += (size_t)npad * HID * 4;
    float* zscalar = (float*)p; p += (size_t)npad * 4;
    float* stats   = (float*)p; p += 4 * 128 * 4;
    float* bnp     = (float*)p; p += 4 * 128 * 4;
    unsigned short* whi = (unsigned short*)p; p += 7 * 4096 * 2;  // W hi frags
    unsigned short* wlo = (unsigned short*)p; p += 7 * 4096 * 2;  // W lo frags
    int* deg     = (int*)p; p += (size_t)n * 4;
    int* rowptr  = (int*)p; p += (size_t)n * 4;
    int* csr_src = (int*)p; p += (size_t)E * 4;

    // CSR-build temporaries alias into zbuf (dead before gatherz writes it)
    int* ebuf  = (int*)zbuf;
    int* cnt   = ebuf + E;
    int* cpart = cnt + NWB;
    int* coff  = cpart + NWB;
    int* bsum  = coff + NWB;
    int* boff  = bsum + nbs2;

    hipMemsetAsync(stats, 0, 4 * 128 * 4, stream);

    // ---- weight prep + CSR build ----
    wprep_kernel<<<7, 256, 0, stream>>>(w2a, w1s, w2s, whi, wlo);
    p1_count_kernel<<<B1, 256, 0, stream>>>(dst, cnt, E, nw, chunk);
    scan_a_kernel<<<nbs2, 256, 0, stream>>>(cnt, cpart, bsum, NWB);
    scan_b_kernel<<<1, 256, 0, stream>>>(bsum, boff, nbs2);
    scan_c_kernel<<<nbs2, 256, 0, stream>>>(cpart, boff, coff, NWB);
    p3_bucket_kernel<<<B1, 256, 0, stream>>>(src, dst, coff, ebuf, E, nw, chunk);
    p4_fine_kernel<<<nw, 256, 0, stream>>>(ebuf, coff, csr_src, rowptr, deg, E, n, nw);

    // ---- Layer 1 (1 -> 64 -> 64) ----
    gather1_kernel<<<(n + 3) / 4, 256, 0, stream>>>(x, rowptr, deg, csr_src, eps, zscalar, n);
    mlp_kernel<<<nblk, 256, 0, stream>>>(zbuf, zscalar, w1a, b1a,
                                         whi, wlo, b1a /*unused*/,
                                         whi /*slot0=w2a*/, wlo, b2a,
                                         hpre, stats, n, 0);
    bnfin_kernel<<<1, 64, 0, stream>>>(stats, gammas, betas, bnp, n);

    // ---- Layers 2-4 ----
    for (int l = 1; l <= 3; ++l) {
        gatherz_kernel<<<(n + 3) / 4, 256, 0, stream>>>(hpre, bnp + (l - 1) * 128,
                                                        rowptr, deg, csr_src, eps, l, zbuf, n);
        mlp_kernel<<<nblk, 256, 0, stream>>>(zbuf, zscalar, w1a, b1a,
                                             whi + (size_t)l * 4096,         // W1 slots 1..3
                                             wlo + (size_t)l * 4096,
                                             b1s + (size_t)(l - 1) * HID,
                                             whi + (size_t)(3 + l) * 4096,   // W2 slots 4..6
                                             wlo + (size_t)(3 + l) * 4096,
                                             b2s + (size_t)(l - 1) * HID,
                                             hpre, stats + l * 128, n, 1);
        bnfin_kernel<<<1, 64, 0, stream>>>(stats + l * 128, gammas + l * HID,
                                           betas + l * HID, bnp + l * 128, n);
    }
    final_kernel<<<(n + 3) / 4, 256, 0, stream>>>(hpre, bnp + 3 * 128, fcw, fcb, out, n);
}

// Round 8
// 406.822 us; speedup vs baseline: 1.8971x; 1.0867x over previous
//
#include <hip/hip_runtime.h>
#include <hip/hip_fp16.h>

#define HID 64
#define BN_EPS 1e-5f
#define WINSH 8          // 256 nodes per dst-window
#define WINSZ 256
#define B1 256           // bucketing blocks (phase 1/3)
#define PIT 72           // LDS pitch in shorts (16B-aligned fragment reads)

typedef short bf16x8 __attribute__((ext_vector_type(8)));
typedef float f32x4 __attribute__((ext_vector_type(4)));

__device__ __forceinline__ unsigned short f2b(float f) {
    unsigned int u = __float_as_uint(f);
    u = (u + 0x7FFF + ((u >> 16) & 1)) >> 16;   // RNE
    return (unsigned short)u;
}
__device__ __forceinline__ float b2f(unsigned short h) {
    return __uint_as_float(((unsigned int)h) << 16);
}
__device__ __forceinline__ f32x4 mfma_bf16(bf16x8 a, bf16x8 b, f32x4 c) {
    return __builtin_amdgcn_mfma_f32_16x16x32_bf16(a, b, c, 0, 0, 0);
}

// ---------------------------------------------------------------------------
// Atomic-free CSR build: two-level counting sort (unchanged).
// ---------------------------------------------------------------------------
__global__ __launch_bounds__(256) void p1_count_kernel(const int* __restrict__ dst,
                                                       int* __restrict__ cnt,
                                                       int E, int nw, int chunk) {
    __shared__ int c[256];
    int tid = threadIdx.x, b = blockIdx.x;
    c[tid] = 0;
    __syncthreads();
    int lo = b * chunk;
    int hi = lo + chunk; if (hi > E) hi = E;
    for (int e = lo + tid; e < hi; e += 256) atomicAdd(&c[dst[e] >> WINSH], 1);
    __syncthreads();
    if (tid < nw) cnt[tid * B1 + b] = c[tid];
}

__global__ __launch_bounds__(256) void scan_a_kernel(const int* __restrict__ in,
                                                     int* __restrict__ partial,
                                                     int* __restrict__ blocksum, int n) {
    __shared__ int sums[256];
    int tid = threadIdx.x;
    int i = blockIdx.x * 256 + tid;
    int v = (i < n) ? in[i] : 0;
    sums[tid] = v;
    __syncthreads();
    for (int off = 1; off < 256; off <<= 1) {
        int t = (tid >= off) ? sums[tid - off] : 0;
        __syncthreads();
        sums[tid] += t;
        __syncthreads();
    }
    if (i < n) partial[i] = sums[tid] - v;
    if (tid == 255) blocksum[blockIdx.x] = sums[255];
}

__global__ __launch_bounds__(256) void scan_b_kernel(const int* __restrict__ blocksum,
                                                     int* __restrict__ blockoff, int nb) {
    __shared__ int s[256];
    __shared__ int carry;
    int tid = threadIdx.x;
    if (tid == 0) carry = 0;
    __syncthreads();
    for (int base = 0; base < nb; base += 256) {
        int i = base + tid;
        int v = (i < nb) ? blocksum[i] : 0;
        s[tid] = v;
        __syncthreads();
        for (int off = 1; off < 256; off <<= 1) {
            int t = (tid >= off) ? s[tid - off] : 0;
            __syncthreads();
            s[tid] += t;
            __syncthreads();
        }
        if (i < nb) blockoff[i] = carry + s[tid] - v;
        __syncthreads();
        if (tid == 0) carry += s[255];
        __syncthreads();
    }
}

__global__ __launch_bounds__(256) void scan_c_kernel(const int* __restrict__ partial,
                                                     const int* __restrict__ blockoff,
                                                     int* __restrict__ outp, int n) {
    int i = blockIdx.x * 256 + threadIdx.x;
    if (i < n) outp[i] = partial[i] + blockoff[blockIdx.x];
}

__global__ __launch_bounds__(256) void p3_bucket_kernel(const int* __restrict__ src,
                                                        const int* __restrict__ dst,
                                                        const int* __restrict__ coff,
                                                        int* __restrict__ ebuf,
                                                        int E, int nw, int chunk) {
    __shared__ int cur[256];
    int tid = threadIdx.x, b = blockIdx.x;
    if (tid < nw) cur[tid] = coff[tid * B1 + b];
    __syncthreads();
    int lo = b * chunk;
    int hi = lo + chunk; if (hi > E) hi = E;
    for (int e = lo + tid; e < hi; e += 256) {
        int d = dst[e];
        int w = d >> WINSH;
        int pos = atomicAdd(&cur[w], 1);           // LDS atomic
        ebuf[pos] = src[e] | ((d & (WINSZ - 1)) << 24);
    }
}

__global__ __launch_bounds__(256) void p4_fine_kernel(const int* __restrict__ ebuf,
                                                      const int* __restrict__ coff,
                                                      int* __restrict__ csr_src,
                                                      int* __restrict__ rowptr,
                                                      int* __restrict__ deg,
                                                      int E, int n, int nw) {
    __shared__ int fcnt[256];
    __shared__ int foff[256];
    int tid = threadIdx.x, w = blockIdx.x;
    int lo = coff[w * B1];
    int hi = (w + 1 < nw) ? coff[(w + 1) * B1] : E;
    fcnt[tid] = 0;
    __syncthreads();
    for (int e = lo + tid; e < hi; e += 256) atomicAdd(&fcnt[(unsigned)ebuf[e] >> 24], 1);
    __syncthreads();
    int v = fcnt[tid];
    foff[tid] = v;
    __syncthreads();
    for (int off = 1; off < 256; off <<= 1) {
        int t = (tid >= off) ? foff[tid - off] : 0;
        __syncthreads();
        foff[tid] += t;
        __syncthreads();
    }
    int myoff = lo + foff[tid] - v;
    int node = w * WINSZ + tid;
    if (node < n) { rowptr[node] = myoff; deg[node] = v; }
    __syncthreads();
    fcnt[tid] = myoff;
    __syncthreads();
    for (int e = lo + tid; e < hi; e += 256) {
        int p = ebuf[e];
        int pos = atomicAdd(&fcnt[(unsigned)p >> 24], 1);   // LDS atomic
        csr_src[pos] = p & 0xFFFFFF;
    }
}

// ---------------------------------------------------------------------------
// Weight prep: split hi/lo bf16, B-fragment order (unchanged).
// ---------------------------------------------------------------------------
__global__ __launch_bounds__(256) void wprep_kernel(const float* __restrict__ w2a,
                                                    const float* __restrict__ w1s,
                                                    const float* __restrict__ w2s,
                                                    unsigned short* __restrict__ whi,
                                                    unsigned short* __restrict__ wlo) {
    int b = blockIdx.x;
    const float* srcm = (b == 0) ? w2a : (b <= 3 ? w1s + (size_t)(b - 1) * 4096
                                                 : w2s + (size_t)(b - 4) * 4096);
    unsigned short* dh = whi + (size_t)b * 4096;
    unsigned short* dl = wlo + (size_t)b * 4096;
    for (int idx = threadIdx.x; idx < 4096; idx += 256) {
        int j = idx & 7;
        int lane = (idx >> 3) & 63;
        int ntkh = idx >> 9;               // 0..7
        int nt = ntkh >> 1, kh = ntkh & 1;
        int nc = nt * 16 + (lane & 15);
        int k = kh * 32 + (lane >> 4) * 8 + j;
        float v = srcm[k * 64 + nc];
        unsigned short h = f2b(v);
        dh[idx] = h;
        dl[idx] = f2b(v - b2f(h));
    }
}

// ---------------------------------------------------------------------------
// Layer 1 scalar aggregation (unchanged)
// ---------------------------------------------------------------------------
__global__ __launch_bounds__(256) void gather1_kernel(const float* __restrict__ x,
                                                      const int* __restrict__ rowptr,
                                                      const int* __restrict__ deg,
                                                      const int* __restrict__ csr_src,
                                                      const float* __restrict__ eps,
                                                      float* __restrict__ zscalar, int n) {
    int node = blockIdx.x * 4 + (threadIdx.x >> 6);
    int lane = threadIdx.x & 63;
    if (node >= n) return;
    int start = __builtin_amdgcn_readfirstlane(rowptr[node]);
    int cnt   = __builtin_amdgcn_readfirstlane(deg[node]);
    float a = 0.f;
    for (int i = lane; i < cnt; i += 64) a += x[csr_src[start + i]];
    for (int off = 32; off > 0; off >>= 1) a += __shfl_xor(a, off);
    if (lane == 0) zscalar[node] = (1.0f + eps[0]) * x[node] + a;
}

// ---------------------------------------------------------------------------
// Layers 2-4 aggregation, BN folded. Neighbors gathered from the FP16
// mirror hh16 (128B/row vs 256B; fp16 = 10 mantissa bits, 8x finer than
// bf16 -> predicted absmax ~0.07 vs bf16's measured 0.50).
// Self term reads fp32 hpre (sequential, exact). fp32 accumulate.
// ---------------------------------------------------------------------------
__global__ __launch_bounds__(256) void gatherz_kernel(const float* __restrict__ hpre,
                                                      const __half* __restrict__ hh16,
                                                      const float* __restrict__ bnp,
                                                      const int* __restrict__ rowptr,
                                                      const int* __restrict__ deg,
                                                      const int* __restrict__ csr_src,
                                                      const float* __restrict__ eps,
                                                      int layer,
                                                      float* __restrict__ zbuf, int n) {
    int node = blockIdx.x * 4 + (threadIdx.x >> 6);
    int lane = threadIdx.x & 63;
    if (node >= n) return;
    int start = __builtin_amdgcn_readfirstlane(rowptr[node]);
    int cnt   = __builtin_amdgcn_readfirstlane(deg[node]);
    float a0 = 0.f, a1 = 0.f, a2 = 0.f, a3 = 0.f;
    float a4 = 0.f, a5 = 0.f, a6 = 0.f, a7 = 0.f;
    int e = 0;
    for (; e + 8 <= cnt; e += 8) {
        int s0 = csr_src[start + e + 0];
        int s1 = csr_src[start + e + 1];
        int s2 = csr_src[start + e + 2];
        int s3 = csr_src[start + e + 3];
        int s4 = csr_src[start + e + 4];
        int s5 = csr_src[start + e + 5];
        int s6 = csr_src[start + e + 6];
        int s7 = csr_src[start + e + 7];
        a0 += __half2float(hh16[(size_t)s0 * HID + lane]);
        a1 += __half2float(hh16[(size_t)s1 * HID + lane]);
        a2 += __half2float(hh16[(size_t)s2 * HID + lane]);
        a3 += __half2float(hh16[(size_t)s3 * HID + lane]);
        a4 += __half2float(hh16[(size_t)s4 * HID + lane]);
        a5 += __half2float(hh16[(size_t)s5 * HID + lane]);
        a6 += __half2float(hh16[(size_t)s6 * HID + lane]);
        a7 += __half2float(hh16[(size_t)s7 * HID + lane]);
    }
    for (; e < cnt; ++e) a0 += __half2float(hh16[(size_t)csr_src[start + e] * HID + lane]);
    float sum = ((a0 + a1) + (a2 + a3)) + ((a4 + a5) + (a6 + a7));
    float ep = 1.0f + eps[layer];
    float sc = bnp[lane], sh = bnp[64 + lane];
    float self = hpre[(size_t)node * HID + lane];
    zbuf[(size_t)node * HID + lane] =
        fmaf(sc, fmaf(ep, self, sum), sh * (ep + (float)cnt));
}

// ---------------------------------------------------------------------------
// MFMA MLP, split-bf16 precision (unchanged math); epilogue also writes
// the fp16 mirror hh16 for the next layer's gather.
// ---------------------------------------------------------------------------
__global__ __launch_bounds__(256) void mlp_kernel(const float* __restrict__ zin,
                                                  const float* __restrict__ zscalar,
                                                  const float* __restrict__ w1a,
                                                  const float* __restrict__ b1a,
                                                  const unsigned short* __restrict__ w1h,
                                                  const unsigned short* __restrict__ w1l,
                                                  const float* __restrict__ b1v,
                                                  const unsigned short* __restrict__ w2h,
                                                  const unsigned short* __restrict__ w2l,
                                                  const float* __restrict__ b2v,
                                                  float* __restrict__ hpre,
                                                  __half* __restrict__ hh16,
                                                  float* __restrict__ stats,
                                                  int n, int mode) {
    __shared__ __align__(16) unsigned short Ah[64 * PIT];
    __shared__ __align__(16) unsigned short Al[64 * PIT];
    __shared__ float ssum[64], ssq[64];

    int tid = threadIdx.x;
    int base = blockIdx.x * 64;

    if (mode) {
        for (int i = tid; i < 4096; i += 256) {
            int nn = i >> 6, k = i & 63;
            float v = zin[(size_t)(base + nn) * HID + k];
            unsigned short h = f2b(v);
            Ah[nn * PIT + k] = h;
            Al[nn * PIT + k] = f2b(v - b2f(h));
        }
    } else {
        for (int i = tid; i < 4096; i += 256) {
            int nn = i >> 6, k = i & 63;
            float zv = zscalar[base + nn];
            float v = fmaxf(fmaf(zv, w1a[k], b1a[k]), 0.f);
            unsigned short h = f2b(v);
            Ah[nn * PIT + k] = h;
            Al[nn * PIT + k] = f2b(v - b2f(h));
        }
    }
    if (tid < 64) { ssum[tid] = 0.f; ssq[tid] = 0.f; }
    __syncthreads();

    int l = tid & 63;
    int m = l & 15;            // A/B free index; D col
    int q = l >> 4;            // quad; D row block
    int m0 = (tid >> 6) * 16;  // wave's node-row block

    const bf16x8* a0h = (const bf16x8*)&Ah[(m0 + m) * PIT + q * 8];
    const bf16x8* a1h = (const bf16x8*)&Ah[(m0 + m) * PIT + 32 + q * 8];
    const bf16x8* a0l = (const bf16x8*)&Al[(m0 + m) * PIT + q * 8];
    const bf16x8* a1l = (const bf16x8*)&Al[(m0 + m) * PIT + 32 + q * 8];

    if (mode) {
        // GEMM1: T = relu(Z @ W1 + b1), split arithmetic
        bf16x8 xa0h = *a0h, xa1h = *a1h, xa0l = *a0l, xa1l = *a1l;
        f32x4 acc[4];
#pragma unroll
        for (int nt = 0; nt < 4; ++nt) {
            size_t fo0 = ((size_t)(nt * 2 + 0) * 64 + l) * 8;
            size_t fo1 = ((size_t)(nt * 2 + 1) * 64 + l) * 8;
            bf16x8 b0h = *(const bf16x8*)(w1h + fo0);
            bf16x8 b1h_ = *(const bf16x8*)(w1h + fo1);
            bf16x8 b0l = *(const bf16x8*)(w1l + fo0);
            bf16x8 b1l_ = *(const bf16x8*)(w1l + fo1);
            f32x4 c = {0.f, 0.f, 0.f, 0.f};
            c = mfma_bf16(xa0h, b0h, c);
            c = mfma_bf16(xa0h, b0l, c);
            c = mfma_bf16(xa0l, b0h, c);
            c = mfma_bf16(xa1h, b1h_, c);
            c = mfma_bf16(xa1h, b1l_, c);
            c = mfma_bf16(xa1l, b1h_, c);
            acc[nt] = c;
        }
#pragma unroll
        for (int nt = 0; nt < 4; ++nt) {
            int col = nt * 16 + m;
            float bv = b1v[col];
#pragma unroll
            for (int r = 0; r < 4; ++r) {
                int row = m0 + q * 4 + r;
                float T = fmaxf(acc[nt][r] + bv, 0.f);
                unsigned short h = f2b(T);
                Ah[row * PIT + col] = h;
                Al[row * PIT + col] = f2b(T - b2f(h));
            }
        }
    }
    __syncthreads();

    // GEMM2: H = relu(T @ W2 + b2), split arithmetic
    {
        bf16x8 xa0h = *a0h, xa1h = *a1h, xa0l = *a0l, xa1l = *a1l;
        f32x4 acc[4];
#pragma unroll
        for (int nt = 0; nt < 4; ++nt) {
            size_t fo0 = ((size_t)(nt * 2 + 0) * 64 + l) * 8;
            size_t fo1 = ((size_t)(nt * 2 + 1) * 64 + l) * 8;
            bf16x8 b0h = *(const bf16x8*)(w2h + fo0);
            bf16x8 b1h_ = *(const bf16x8*)(w2h + fo1);
            bf16x8 b0l = *(const bf16x8*)(w2l + fo0);
            bf16x8 b1l_ = *(const bf16x8*)(w2l + fo1);
            f32x4 c = {0.f, 0.f, 0.f, 0.f};
            c = mfma_bf16(xa0h, b0h, c);
            c = mfma_bf16(xa0h, b0l, c);
            c = mfma_bf16(xa0l, b0h, c);
            c = mfma_bf16(xa1h, b1h_, c);
            c = mfma_bf16(xa1h, b1l_, c);
            c = mfma_bf16(xa1l, b1h_, c);
            acc[nt] = c;
        }
#pragma unroll
        for (int nt = 0; nt < 4; ++nt) {
            int col = nt * 16 + m;
            float bv = b2v[col];
            float cs = 0.f, cq = 0.f;
#pragma unroll
            for (int r = 0; r < 4; ++r) {
                int node = base + m0 + q * 4 + r;
                float h = fmaxf(acc[nt][r] + bv, 0.f);
                if (node < n) {
                    hpre[(size_t)node * HID + col] = h;
                    hh16[(size_t)node * HID + col] = __float2half(h);
                    cs += h;
                    cq = fmaf(h, h, cq);
                }
            }
            cs += __shfl_xor(cs, 16); cs += __shfl_xor(cs, 32);
            cq += __shfl_xor(cq, 16); cq += __shfl_xor(cq, 32);
            if (q == 0) {
                atomicAdd(&ssum[col], cs);
                atomicAdd(&ssq[col], cq);
            }
        }
    }
    __syncthreads();
    if (tid < 64) {
        atomicAdd(&stats[tid], ssum[tid]);
        atomicAdd(&stats[64 + tid], ssq[tid]);
    }
}

// ---------------------------------------------------------------------------
// BN finalize (unchanged)
// ---------------------------------------------------------------------------
__global__ __launch_bounds__(64) void bnfin_kernel(const float* __restrict__ stats,
                                                   const float* __restrict__ gamma,
                                                   const float* __restrict__ beta,
                                                   float* __restrict__ bnp, int n) {
    int f = threadIdx.x;
    float inv_n = 1.0f / (float)n;
    float mu = stats[f] * inv_n;
    float var = stats[64 + f] * inv_n - mu * mu;
    float inv = rsqrtf(var + BN_EPS);
    float sc = gamma[f] * inv;
    float sh = beta[f] - mu * sc;
    bnp[f] = sc;
    bnp[64 + f] = sh;
}

// ---------------------------------------------------------------------------
// Final (unchanged; reads fp32 hpre of layer 4)
// ---------------------------------------------------------------------------
__global__ __launch_bounds__(256) void final_kernel(const float* __restrict__ hpre,
                                                    const float* __restrict__ bnp,
                                                    const float* __restrict__ fcw,
                                                    const float* __restrict__ fcb,
                                                    float* __restrict__ out, int n) {
    int wave = threadIdx.x >> 6;
    int lane = threadIdx.x & 63;
    int node = blockIdx.x * 4 + wave;
    if (node < n) {
        float v = hpre[(size_t)node * HID + lane];
        float t = fmaf(v, bnp[lane], bnp[64 + lane]) * fcw[lane];
        for (int off = 32; off > 0; off >>= 1) t += __shfl_xor(t, off);
        if (lane == 0) out[node] = t + fcb[0];
    }
}

// ---------------------------------------------------------------------------
extern "C" void kernel_launch(void* const* d_in, const int* in_sizes, int n_in,
                              void* d_out, int out_size, void* d_ws, size_t ws_size,
                              hipStream_t stream) {
    const float* x      = (const float*)d_in[0];
    const int*   ei     = (const int*)d_in[1];
    const float* w1a    = (const float*)d_in[2];
    const float* b1a    = (const float*)d_in[3];
    const float* w2a    = (const float*)d_in[4];
    const float* b2a    = (const float*)d_in[5];
    const float* w1s    = (const float*)d_in[6];
    const float* b1s    = (const float*)d_in[7];
    const float* w2s    = (const float*)d_in[8];
    const float* b2s    = (const float*)d_in[9];
    const float* eps    = (const float*)d_in[10];
    const float* gammas = (const float*)d_in[11];
    const float* betas  = (const float*)d_in[12];
    const float* fcw    = (const float*)d_in[13];
    const float* fcb    = (const float*)d_in[14];
    float* out = (float*)d_out;

    int n = in_sizes[0];          // 50000
    int E = in_sizes[1] / 2;      // 1600000
    int npad = ((n + 63) / 64) * 64;
    int nblk = npad / 64;

    int nw = (n + WINSZ - 1) >> WINSH;      // 196 windows
    int NWB = nw * B1;
    int chunk = (E + B1 - 1) / B1;
    int nbs2 = (NWB + 255) / 256;

    const int* src = ei;
    const int* dst = ei + E;

    char* p = (char*)d_ws;
    float* zbuf    = (float*)p; p += (size_t)npad * HID * 4;   // aliased by CSR temps
    float* hpre    = (float*)p; p += (size_t)npad * HID * 4;
    __half* hh16   = (__half*)p; p += (size_t)npad * HID * 2;
    float* zscalar = (float*)p; p += (size_t)npad * 4;
    float* stats   = (float*)p; p += 4 * 128 * 4;
    float* bnp     = (float*)p; p += 4 * 128 * 4;
    unsigned short* whi = (unsigned short*)p; p += 7 * 4096 * 2;  // W hi frags
    unsigned short* wlo = (unsigned short*)p; p += 7 * 4096 * 2;  // W lo frags
    int* deg     = (int*)p; p += (size_t)n * 4;
    int* rowptr  = (int*)p; p += (size_t)n * 4;
    int* csr_src = (int*)p; p += (size_t)E * 4;

    // CSR-build temporaries alias into zbuf (dead before gatherz writes it)
    int* ebuf  = (int*)zbuf;
    int* cnt   = ebuf + E;
    int* cpart = cnt + NWB;
    int* coff  = cpart + NWB;
    int* bsum  = coff + NWB;
    int* boff  = bsum + nbs2;

    hipMemsetAsync(stats, 0, 4 * 128 * 4, stream);

    // ---- weight prep + CSR build ----
    wprep_kernel<<<7, 256, 0, stream>>>(w2a, w1s, w2s, whi, wlo);
    p1_count_kernel<<<B1, 256, 0, stream>>>(dst, cnt, E, nw, chunk);
    scan_a_kernel<<<nbs2, 256, 0, stream>>>(cnt, cpart, bsum, NWB);
    scan_b_kernel<<<1, 256, 0, stream>>>(bsum, boff, nbs2);
    scan_c_kernel<<<nbs2, 256, 0, stream>>>(cpart, boff, coff, NWB);
    p3_bucket_kernel<<<B1, 256, 0, stream>>>(src, dst, coff, ebuf, E, nw, chunk);
    p4_fine_kernel<<<nw, 256, 0, stream>>>(ebuf, coff, csr_src, rowptr, deg, E, n, nw);

    // ---- Layer 1 (1 -> 64 -> 64) ----
    gather1_kernel<<<(n + 3) / 4, 256, 0, stream>>>(x, rowptr, deg, csr_src, eps, zscalar, n);
    mlp_kernel<<<nblk, 256, 0, stream>>>(zbuf, zscalar, w1a, b1a,
                                         whi, wlo, b1a /*unused*/,
                                         whi /*slot0=w2a*/, wlo, b2a,
                                         hpre, hh16, stats, n, 0);
    bnfin_kernel<<<1, 64, 0, stream>>>(stats, gammas, betas, bnp, n);

    // ---- Layers 2-4 ----
    for (int l = 1; l <= 3; ++l) {
        gatherz_kernel<<<(n + 3) / 4, 256, 0, stream>>>(hpre, hh16, bnp + (l - 1) * 128,
                                                        rowptr, deg, csr_src, eps, l, zbuf, n);
        mlp_kernel<<<nblk, 256, 0, stream>>>(zbuf, zscalar, w1a, b1a,
                                             whi + (size_t)l * 4096,         // W1 slots 1..3
                                             wlo + (size_t)l * 4096,
                                             b1s + (size_t)(l - 1) * HID,
                                             whi + (size_t)(3 + l) * 4096,   // W2 slots 4..6
                                             wlo + (size_t)(3 + l) * 4096,
                                             b2s + (size_t)(l - 1) * HID,
                                             hpre, hh16, stats + l * 128, n, 1);
        bnfin_kernel<<<1, 64, 0, stream>>>(stats + l * 128, gammas + l * HID,
                                           betas + l * HID, bnp + l * 128, n);
    }
    final_kernel<<<(n + 3) / 4, 256, 0, stream>>>(hpre, bnp + 3 * 128, fcw, fcb, out, n);
}